// Round 2
// baseline (549.301 us; speedup 1.0000x reference)
//
#include <hip/hip_runtime.h>
#include <cstddef>

#define HH 512
#define WW 512
#define BB 8
#define T  32

// ws layout (floats): [0..72)   keff_edge  (3*3 spatial)*8ch   (depthwise∘pointwise, exact)
//                     [72..193) Keff11     11*11               (curve0∘curve1∘Σcurve2, composed)

__global__ __launch_bounds__(256) void precompute_kernels(
    const float* __restrict__ kd,   // (3,3,1,8)
    const float* __restrict__ kp,   // (1,1,8,8)
    const float* __restrict__ k0,   // (5,5,1,8)
    const float* __restrict__ k1,   // (5,5,8,8)
    const float* __restrict__ k2,   // (3,3,8,16)
    float* __restrict__ ws) {
  __shared__ float k9[648];   // Keff9[(a*9+b)*8 + c1]  (curve0∘curve1)
  __shared__ float k2s[72];   // Σ_c2 k2[(t*3+v)*8+c1]
  const int tid = threadIdx.x;

  for (int idx = tid; idx < 72; idx += 256) {
    int c = idx & 7, pq = idx >> 3;
    float s = 0.f;
    for (int c0 = 0; c0 < 8; ++c0) s = fmaf(kd[pq * 8 + c0], kp[c0 * 8 + c], s);
    ws[idx] = s;
  }
  for (int idx = tid; idx < 72; idx += 256) {
    int c1 = idx & 7, tv = idx >> 3;
    float s = 0.f;
    for (int c2 = 0; c2 < 16; ++c2) s += k2[(tv * 8 + c1) * 16 + c2];
    k2s[idx] = s;
  }
  for (int idx = tid; idx < 648; idx += 256) {
    int c1 = idx & 7;
    int ab = idx >> 3;
    int a = ab / 9, b = ab % 9;
    float s = 0.f;
    int plo = a > 4 ? a - 4 : 0, phi = a < 4 ? a : 4;
    int qlo = b > 4 ? b - 4 : 0, qhi = b < 4 ? b : 4;
    for (int p = plo; p <= phi; ++p)
      for (int q = qlo; q <= qhi; ++q) {
        int r = a - p, sx = b - q;
        const float* k0p = &k0[(p * 5 + q) * 8];
        const float* k1p = &k1[((r * 5 + sx) * 8) * 8 + c1];
        for (int c0 = 0; c0 < 8; ++c0) s = fmaf(k0p[c0], k1p[c0 * 8], s);
      }
    k9[idx] = s;
  }
  __syncthreads();
  for (int idx = tid; idx < 121; idx += 256) {
    int A = idx / 11, B = idx % 11;
    float s = 0.f;
    int tlo = A > 8 ? A - 8 : 0, thi = A < 2 ? A : 2;
    int vlo = B > 8 ? B - 8 : 0, vhi = B < 2 ? B : 2;
    for (int t = tlo; t <= thi; ++t)
      for (int v = vlo; v <= vhi; ++v) {
        int a = A - t, b = B - v;
        for (int c1 = 0; c1 < 8; ++c1)
          s = fmaf(k9[(a * 9 + b) * 8 + c1], k2s[(t * 3 + v) * 8 + c1], s);
      }
    ws[72 + idx] = s;
  }
}

// Fused main kernel: one 32x32 output tile per block, 256 threads.
// __launch_bounds__(256,4): cap VGPR at 128 -> 4 blocks/CU (16 waves) vs 3 at 144.
__global__ __launch_bounds__(256, 4) void forcing_main(
    const float* __restrict__ u, const float* __restrict__ img,
    const float* __restrict__ kx, const float* __restrict__ ky,
    const float* __restrict__ sm, const float* __restrict__ kk,
    const float* __restrict__ ws, float* __restrict__ out) {
  __shared__ float su[46][48];   // u tile, radius-7 halo; stride 48 -> 16B-aligned float4 rows
  __shared__ float si[36][37];   // image tile, radius-2 halo (zero-padded)
  __shared__ float se[34][35];   // edges tile, radius-1 halo (stride 35: 2-way banks = free)
  __shared__ float sk[36][37];   // (kappa_pre * kappa_kernel) tile, radius-2 halo
  __shared__ float w_edge[72];
  __shared__ float w_kx[288];
  __shared__ float w_ky[288];
  __shared__ float w_k11[124];
  __shared__ float w_sm[28];

  const int bx = blockIdx.x * T;
  const int by = blockIdx.y * T;
  const int b  = blockIdx.z;
  const int tid = threadIdx.x;
  const float* ub = u   + (size_t)b * HH * WW;
  const float* ib = img + (size_t)b * HH * WW;

  // ---- stage weights + u halo + image halo ----
  for (int i = tid; i < 72; i += 256)  w_edge[i] = ws[i];
  for (int i = tid; i < 121; i += 256) w_k11[i]  = ws[72 + i];
  for (int i = tid; i < 288; i += 256) { w_kx[i] = kx[i]; w_ky[i] = ky[i]; }
  if (tid < 25) w_sm[tid] = sm[tid];

  for (int idx = tid; idx < 46 * 46; idx += 256) {
    int i = idx / 46, j = idx % 46;
    int gy = by - 7 + i, gx = bx - 7 + j;
    float v = 0.f;
    if ((unsigned)gy < HH && (unsigned)gx < WW) v = ub[gy * WW + gx];
    su[i][j] = v;
  }
  for (int idx = tid; idx < 36 * 36; idx += 256) {
    int i = idx / 36, j = idx % 36;
    int gy = by - 2 + i, gx = bx - 2 + j;
    float v = 0.f;
    if ((unsigned)gy < HH && (unsigned)gx < WW) v = ib[gy * WW + gx];
    si[i][j] = v;
  }
  __syncthreads();

  // ---- edges tile: softsign(Σ_c relu(conv3x3(image, keff_edge)))  on 34x34 ----
  // strips of 4 px along x: 34 rows x 9 strips = 306 items
  for (int idx = tid; idx < 34 * 9; idx += 256) {
    int i = idx / 9, j0 = (idx % 9) * 4;       // edge pos (by-1+i, bx-1+j0+t)
    float acc[8][4];
    #pragma unroll
    for (int c = 0; c < 8; ++c)
      #pragma unroll
      for (int t = 0; t < 4; ++t) acc[c][t] = 0.f;
    #pragma unroll
    for (int p = 0; p < 3; ++p) {
      float r[6];
      #pragma unroll
      for (int t = 0; t < 6; ++t) r[t] = si[i + p][j0 + t];
      #pragma unroll
      for (int q = 0; q < 3; ++q) {
        const float4 w0 = *reinterpret_cast<const float4*>(&w_edge[(p * 3 + q) * 8]);
        const float4 w1 = *reinterpret_cast<const float4*>(&w_edge[(p * 3 + q) * 8 + 4]);
        #pragma unroll
        for (int t = 0; t < 4; ++t) {
          float v = r[q + t];
          acc[0][t] = fmaf(v, w0.x, acc[0][t]);
          acc[1][t] = fmaf(v, w0.y, acc[1][t]);
          acc[2][t] = fmaf(v, w0.z, acc[2][t]);
          acc[3][t] = fmaf(v, w0.w, acc[3][t]);
          acc[4][t] = fmaf(v, w1.x, acc[4][t]);
          acc[5][t] = fmaf(v, w1.y, acc[5][t]);
          acc[6][t] = fmaf(v, w1.z, acc[6][t]);
          acc[7][t] = fmaf(v, w1.w, acc[7][t]);
        }
      }
    }
    int gy = by - 1 + i;
    #pragma unroll
    for (int t = 0; t < 4; ++t) {
      int j = j0 + t;
      if (j < 34) {
        int gx = bx - 1 + j;
        float val = 0.f;
        if ((unsigned)gy < HH && (unsigned)gx < WW) {
          float e = 0.f;
          #pragma unroll
          for (int c = 0; c < 8; ++c) e += fmaxf(acc[c][t], 0.f);
          val = e / (1.f + e);                // soft_sign, e >= 0
        }
        se[i][j] = val;
      }
    }
  }

  // ---- kappa_pre tile: (conv11x11(u, Keff11)) * kappa_kernel  on 36x36 ----
  for (int idx = tid; idx < 36 * 9; idx += 256) {
    int i = idx / 9, js = (idx % 9) * 4;     // pos (by-2+i, bx-2+js..+3)
    float o0 = 0.f, o1 = 0.f, o2 = 0.f, o3 = 0.f;
    #pragma unroll
    for (int A = 0; A < 11; ++A) {
      const float* row = &su[i + A][js];      // 16B-aligned (stride 48, js%4==0)
      float4 v0 = *reinterpret_cast<const float4*>(row);
      float4 v1 = *reinterpret_cast<const float4*>(row + 4);
      float4 v2 = *reinterpret_cast<const float4*>(row + 8);
      float r[14] = {v0.x, v0.y, v0.z, v0.w, v1.x, v1.y, v1.z, v1.w,
                     v2.x, v2.y, v2.z, v2.w, row[12], row[13]};
      #pragma unroll
      for (int B2 = 0; B2 < 11; ++B2) {
        float w = w_k11[A * 11 + B2];
        o0 = fmaf(r[B2],     w, o0);
        o1 = fmaf(r[B2 + 1], w, o1);
        o2 = fmaf(r[B2 + 2], w, o2);
        o3 = fmaf(r[B2 + 3], w, o3);
      }
    }
    int gy = by - 2 + i;
    float o[4] = {o0, o1, o2, o3};
    #pragma unroll
    for (int t = 0; t < 4; ++t) {
      int gx = bx - 2 + js + t;
      float val = 0.f;
      if ((unsigned)gy < HH && (unsigned)gx < WW) val = o[t] * kk[gy * WW + gx];
      sk[i][js + t] = val;
    }
  }
  __syncthreads();

  // ---- final: grads (32ch relu-sum) + smoother + combine; 1x4 px strip per thread ----
  {
    const int oy = tid >> 3;
    const int ox = (tid & 7) * 4;
    const int gy = by + oy;
    const int gx = bx + ox;

    float e[3][6];
    #pragma unroll
    for (int p = 0; p < 3; ++p)
      #pragma unroll
      for (int t = 0; t < 6; ++t) e[p][t] = se[oy + p][ox + t];

    const float4* wx4 = reinterpret_cast<const float4*>(w_kx);
    const float4* wy4 = reinterpret_cast<const float4*>(w_ky);

    float gxa[4] = {0.f, 0.f, 0.f, 0.f};
    float gya[4] = {0.f, 0.f, 0.f, 0.f};
    #pragma unroll
    for (int cq = 0; cq < 8; ++cq) {        // channel quads: c = cq*4 + cc
      float sx[4][4], sy[4][4];             // [cc][t]
      #pragma unroll
      for (int cc = 0; cc < 4; ++cc)
        #pragma unroll
        for (int t = 0; t < 4; ++t) { sx[cc][t] = 0.f; sy[cc][t] = 0.f; }
      #pragma unroll
      for (int p = 0; p < 3; ++p)
        #pragma unroll
        for (int q = 0; q < 3; ++q) {
          float4 wx = wx4[(p * 3 + q) * 8 + cq];   // broadcast b128
          float4 wy = wy4[(p * 3 + q) * 8 + cq];
          #pragma unroll
          for (int t = 0; t < 4; ++t) {
            float ev = e[p][q + t];
            sx[0][t] = fmaf(ev, wx.x, sx[0][t]);
            sx[1][t] = fmaf(ev, wx.y, sx[1][t]);
            sx[2][t] = fmaf(ev, wx.z, sx[2][t]);
            sx[3][t] = fmaf(ev, wx.w, sx[3][t]);
            sy[0][t] = fmaf(ev, wy.x, sy[0][t]);
            sy[1][t] = fmaf(ev, wy.y, sy[1][t]);
            sy[2][t] = fmaf(ev, wy.z, sy[2][t]);
            sy[3][t] = fmaf(ev, wy.w, sy[3][t]);
          }
        }
      #pragma unroll
      for (int cc = 0; cc < 4; ++cc)
        #pragma unroll
        for (int t = 0; t < 4; ++t) {
          gxa[t] += fmaxf(sx[cc][t], 0.f);
          gya[t] += fmaxf(sy[cc][t], 0.f);
        }
    }

    float res[4];
    #pragma unroll
    for (int t = 0; t < 4; ++t) {
      float kap = 0.f;
      #pragma unroll
      for (int m = 0; m < 5; ++m)
        #pragma unroll
        for (int n = 0; n < 5; ++n)
          kap = fmaf(sk[oy + m][ox + t + n], w_sm[m * 5 + n], kap);

      float uc = su[oy + 7][ox + 7 + t];
      float xp = uc - su[oy + 7][ox + 6 + t];   // u[y,x] - u[y,x-1]
      float yp = uc - su[oy + 8][ox + 7 + t];   // u[y,x] - u[y+1,x]
      float ec = se[oy + 1][ox + 1 + t];
      // fxn, fyn are identically 0 (grads are sums of relus >= 0)
      res[t] = uc + gxa[t] * xp + gya[t] * yp + ec + kap;
    }

    float4 r4 = make_float4(res[0], res[1], res[2], res[3]);
    *reinterpret_cast<float4*>(&out[((size_t)b * HH + gy) * WW + gx]) = r4;
  }
}

extern "C" void kernel_launch(void* const* d_in, const int* in_sizes, int n_in,
                              void* d_out, int out_size, void* d_ws, size_t ws_size,
                              hipStream_t stream) {
  const float* u   = (const float*)d_in[0];
  const float* img = (const float*)d_in[1];
  const float* kx  = (const float*)d_in[2];
  const float* ky  = (const float*)d_in[3];
  const float* kd  = (const float*)d_in[4];
  const float* kp  = (const float*)d_in[5];
  const float* k0  = (const float*)d_in[6];
  const float* k1  = (const float*)d_in[7];
  const float* k2  = (const float*)d_in[8];
  const float* sm  = (const float*)d_in[9];
  const float* kk  = (const float*)d_in[10];
  float* out = (float*)d_out;
  float* ws  = (float*)d_ws;

  precompute_kernels<<<1, 256, 0, stream>>>(kd, kp, k0, k1, k2, ws);
  dim3 grid(WW / T, HH / T, BB);
  forcing_main<<<grid, 256, 0, stream>>>(u, img, kx, ky, sm, kk, ws, out);
}

// Round 3
// 247.127 us; speedup vs baseline: 2.2227x; 2.2227x over previous
//
#include <hip/hip_runtime.h>
#include <cstddef>

#define HH 512
#define WW 512
#define BB 8
#define T  32

// ws layout (floats): [0..72)   keff_edge  (3*3 spatial)*8ch   (depthwise∘pointwise, exact)
//                     [72..193) Keff11     11*11               (curve0∘curve1∘Σcurve2, composed)

__global__ __launch_bounds__(256) void precompute_kernels(
    const float* __restrict__ kd,   // (3,3,1,8)
    const float* __restrict__ kp,   // (1,1,8,8)
    const float* __restrict__ k0,   // (5,5,1,8)
    const float* __restrict__ k1,   // (5,5,8,8)
    const float* __restrict__ k2,   // (3,3,8,16)
    float* __restrict__ ws) {
  __shared__ float k9[648];   // Keff9[(a*9+b)*8 + c1]  (curve0∘curve1)
  __shared__ float k2s[72];   // Σ_c2 k2[(t*3+v)*8+c1]
  const int tid = threadIdx.x;

  for (int idx = tid; idx < 72; idx += 256) {
    int c = idx & 7, pq = idx >> 3;
    float s = 0.f;
    for (int c0 = 0; c0 < 8; ++c0) s = fmaf(kd[pq * 8 + c0], kp[c0 * 8 + c], s);
    ws[idx] = s;
  }
  for (int idx = tid; idx < 72; idx += 256) {
    int c1 = idx & 7, tv = idx >> 3;
    float s = 0.f;
    for (int c2 = 0; c2 < 16; ++c2) s += k2[(tv * 8 + c1) * 16 + c2];
    k2s[idx] = s;
  }
  for (int idx = tid; idx < 648; idx += 256) {
    int c1 = idx & 7;
    int ab = idx >> 3;
    int a = ab / 9, b = ab % 9;
    float s = 0.f;
    int plo = a > 4 ? a - 4 : 0, phi = a < 4 ? a : 4;
    int qlo = b > 4 ? b - 4 : 0, qhi = b < 4 ? b : 4;
    for (int p = plo; p <= phi; ++p)
      for (int q = qlo; q <= qhi; ++q) {
        int r = a - p, sx = b - q;
        const float* k0p = &k0[(p * 5 + q) * 8];
        const float* k1p = &k1[((r * 5 + sx) * 8) * 8 + c1];
        for (int c0 = 0; c0 < 8; ++c0) s = fmaf(k0p[c0], k1p[c0 * 8], s);
      }
    k9[idx] = s;
  }
  __syncthreads();
  for (int idx = tid; idx < 121; idx += 256) {
    int A = idx / 11, B = idx % 11;
    float s = 0.f;
    int tlo = A > 8 ? A - 8 : 0, thi = A < 2 ? A : 2;
    int vlo = B > 8 ? B - 8 : 0, vhi = B < 2 ? B : 2;
    for (int t = tlo; t <= thi; ++t)
      for (int v = vlo; v <= vhi; ++v) {
        int a = A - t, b = B - v;
        for (int c1 = 0; c1 < 8; ++c1)
          s = fmaf(k9[(a * 9 + b) * 8 + c1], k2s[(t * 3 + v) * 8 + c1], s);
      }
    ws[72 + idx] = s;
  }
}

// Fused main kernel: one 32x32 output tile per block, 256 threads.
// NOTE: no min-waves clause! (256,4) forced VGPR<=64 -> 1.4 GB of scratch
// spill traffic, 3x regression (R2). Natural allocation ~150-170 VGPR,
// 3 waves/SIMD, zero spill.
__global__ __launch_bounds__(256) void forcing_main(
    const float* __restrict__ u, const float* __restrict__ img,
    const float* __restrict__ kx, const float* __restrict__ ky,
    const float* __restrict__ sm, const float* __restrict__ kk,
    const float* __restrict__ ws, float* __restrict__ out) {
  __shared__ float su[46][48];   // u tile, radius-7 halo; stride 48 -> 16B-aligned float4 rows
  __shared__ float si[36][37];   // image tile, radius-2 halo (zero-padded)
  __shared__ float se[34][35];   // edges tile, radius-1 halo
  __shared__ float sk[36][37];   // (kappa_pre * kappa_kernel) tile, radius-2 halo
  __shared__ float w_edge[72];
  __shared__ float w_kx[288];
  __shared__ float w_ky[288];
  __shared__ float w_k11[124];
  __shared__ float w_sm[28];

  const int bx = blockIdx.x * T;
  const int by = blockIdx.y * T;
  const int b  = blockIdx.z;
  const int tid = threadIdx.x;
  const float* ub = u   + (size_t)b * HH * WW;
  const float* ib = img + (size_t)b * HH * WW;

  // ---- stage weights + u halo + image halo ----
  for (int i = tid; i < 72; i += 256)  w_edge[i] = ws[i];
  for (int i = tid; i < 121; i += 256) w_k11[i]  = ws[72 + i];
  for (int i = tid; i < 288; i += 256) { w_kx[i] = kx[i]; w_ky[i] = ky[i]; }
  if (tid < 25) w_sm[tid] = sm[tid];

  for (int idx = tid; idx < 46 * 46; idx += 256) {
    int i = idx / 46, j = idx % 46;
    int gy = by - 7 + i, gx = bx - 7 + j;
    float v = 0.f;
    if ((unsigned)gy < HH && (unsigned)gx < WW) v = ub[gy * WW + gx];
    su[i][j] = v;
  }
  for (int idx = tid; idx < 36 * 36; idx += 256) {
    int i = idx / 36, j = idx % 36;
    int gy = by - 2 + i, gx = bx - 2 + j;
    float v = 0.f;
    if ((unsigned)gy < HH && (unsigned)gx < WW) v = ib[gy * WW + gx];
    si[i][j] = v;
  }
  __syncthreads();

  // ---- edges tile: softsign(Σ_c relu(conv3x3(image, keff_edge)))  on 34x34 ----
  // strips of 4 px along x: 34 rows x 9 strips = 306 items
  for (int idx = tid; idx < 34 * 9; idx += 256) {
    int i = idx / 9, j0 = (idx % 9) * 4;       // edge pos (by-1+i, bx-1+j0+t)
    float acc[8][4];
    #pragma unroll
    for (int c = 0; c < 8; ++c)
      #pragma unroll
      for (int t = 0; t < 4; ++t) acc[c][t] = 0.f;
    #pragma unroll
    for (int p = 0; p < 3; ++p) {
      float r[6];
      #pragma unroll
      for (int t = 0; t < 6; ++t) r[t] = si[i + p][j0 + t];
      #pragma unroll
      for (int q = 0; q < 3; ++q) {
        const float4 w0 = *reinterpret_cast<const float4*>(&w_edge[(p * 3 + q) * 8]);
        const float4 w1 = *reinterpret_cast<const float4*>(&w_edge[(p * 3 + q) * 8 + 4]);
        #pragma unroll
        for (int t = 0; t < 4; ++t) {
          float v = r[q + t];
          acc[0][t] = fmaf(v, w0.x, acc[0][t]);
          acc[1][t] = fmaf(v, w0.y, acc[1][t]);
          acc[2][t] = fmaf(v, w0.z, acc[2][t]);
          acc[3][t] = fmaf(v, w0.w, acc[3][t]);
          acc[4][t] = fmaf(v, w1.x, acc[4][t]);
          acc[5][t] = fmaf(v, w1.y, acc[5][t]);
          acc[6][t] = fmaf(v, w1.z, acc[6][t]);
          acc[7][t] = fmaf(v, w1.w, acc[7][t]);
        }
      }
    }
    int gy = by - 1 + i;
    #pragma unroll
    for (int t = 0; t < 4; ++t) {
      int j = j0 + t;
      if (j < 34) {
        int gx = bx - 1 + j;
        float val = 0.f;
        if ((unsigned)gy < HH && (unsigned)gx < WW) {
          float e = 0.f;
          #pragma unroll
          for (int c = 0; c < 8; ++c) e += fmaxf(acc[c][t], 0.f);
          val = e / (1.f + e);                // soft_sign, e >= 0
        }
        se[i][j] = val;
      }
    }
  }

  // ---- kappa_pre tile: (conv11x11(u, Keff11)) * kappa_kernel  on 36x36 ----
  for (int idx = tid; idx < 36 * 9; idx += 256) {
    int i = idx / 9, js = (idx % 9) * 4;     // pos (by-2+i, bx-2+js..+3)
    float o0 = 0.f, o1 = 0.f, o2 = 0.f, o3 = 0.f;
    #pragma unroll
    for (int A = 0; A < 11; ++A) {
      const float* row = &su[i + A][js];      // 16B-aligned (stride 48, js%4==0)
      float4 v0 = *reinterpret_cast<const float4*>(row);
      float4 v1 = *reinterpret_cast<const float4*>(row + 4);
      float4 v2 = *reinterpret_cast<const float4*>(row + 8);
      float r[14] = {v0.x, v0.y, v0.z, v0.w, v1.x, v1.y, v1.z, v1.w,
                     v2.x, v2.y, v2.z, v2.w, row[12], row[13]};
      #pragma unroll
      for (int B2 = 0; B2 < 11; ++B2) {
        float w = w_k11[A * 11 + B2];
        o0 = fmaf(r[B2],     w, o0);
        o1 = fmaf(r[B2 + 1], w, o1);
        o2 = fmaf(r[B2 + 2], w, o2);
        o3 = fmaf(r[B2 + 3], w, o3);
      }
    }
    int gy = by - 2 + i;
    float o[4] = {o0, o1, o2, o3};
    #pragma unroll
    for (int t = 0; t < 4; ++t) {
      int gx = bx - 2 + js + t;
      float val = 0.f;
      if ((unsigned)gy < HH && (unsigned)gx < WW) val = o[t] * kk[gy * WW + gx];
      sk[i][js + t] = val;
    }
  }
  __syncthreads();

  // ---- final: grads (32ch relu-sum) + smoother + combine; 1x4 px strip per thread ----
  {
    const int oy = tid >> 3;
    const int ox = (tid & 7) * 4;
    const int gy = by + oy;
    const int gx = bx + ox;

    float e[3][6];
    #pragma unroll
    for (int p = 0; p < 3; ++p)
      #pragma unroll
      for (int t = 0; t < 6; ++t) e[p][t] = se[oy + p][ox + t];

    const float4* wx4 = reinterpret_cast<const float4*>(w_kx);
    const float4* wy4 = reinterpret_cast<const float4*>(w_ky);

    float gxa[4] = {0.f, 0.f, 0.f, 0.f};
    float gya[4] = {0.f, 0.f, 0.f, 0.f};
    #pragma unroll
    for (int cq = 0; cq < 8; ++cq) {        // channel quads: c = cq*4 + cc
      float sx[4][4], sy[4][4];             // [cc][t]
      #pragma unroll
      for (int cc = 0; cc < 4; ++cc)
        #pragma unroll
        for (int t = 0; t < 4; ++t) { sx[cc][t] = 0.f; sy[cc][t] = 0.f; }
      #pragma unroll
      for (int p = 0; p < 3; ++p)
        #pragma unroll
        for (int q = 0; q < 3; ++q) {
          float4 wx = wx4[(p * 3 + q) * 8 + cq];   // broadcast b128
          float4 wy = wy4[(p * 3 + q) * 8 + cq];
          #pragma unroll
          for (int t = 0; t < 4; ++t) {
            float ev = e[p][q + t];
            sx[0][t] = fmaf(ev, wx.x, sx[0][t]);
            sx[1][t] = fmaf(ev, wx.y, sx[1][t]);
            sx[2][t] = fmaf(ev, wx.z, sx[2][t]);
            sx[3][t] = fmaf(ev, wx.w, sx[3][t]);
            sy[0][t] = fmaf(ev, wy.x, sy[0][t]);
            sy[1][t] = fmaf(ev, wy.y, sy[1][t]);
            sy[2][t] = fmaf(ev, wy.z, sy[2][t]);
            sy[3][t] = fmaf(ev, wy.w, sy[3][t]);
          }
        }
      #pragma unroll
      for (int cc = 0; cc < 4; ++cc)
        #pragma unroll
        for (int t = 0; t < 4; ++t) {
          gxa[t] += fmaxf(sx[cc][t], 0.f);
          gya[t] += fmaxf(sy[cc][t], 0.f);
        }
    }

    float res[4];
    #pragma unroll
    for (int t = 0; t < 4; ++t) {
      float kap = 0.f;
      #pragma unroll
      for (int m = 0; m < 5; ++m)
        #pragma unroll
        for (int n = 0; n < 5; ++n)
          kap = fmaf(sk[oy + m][ox + t + n], w_sm[m * 5 + n], kap);

      float uc = su[oy + 7][ox + 7 + t];
      float xp = uc - su[oy + 7][ox + 6 + t];   // u[y,x] - u[y,x-1]
      float yp = uc - su[oy + 8][ox + 7 + t];   // u[y,x] - u[y+1,x]
      float ec = se[oy + 1][ox + 1 + t];
      // fxn, fyn are identically 0 (grads are sums of relus >= 0)
      res[t] = uc + gxa[t] * xp + gya[t] * yp + ec + kap;
    }

    float4 r4 = make_float4(res[0], res[1], res[2], res[3]);
    *reinterpret_cast<float4*>(&out[((size_t)b * HH + gy) * WW + gx]) = r4;
  }
}

extern "C" void kernel_launch(void* const* d_in, const int* in_sizes, int n_in,
                              void* d_out, int out_size, void* d_ws, size_t ws_size,
                              hipStream_t stream) {
  const float* u   = (const float*)d_in[0];
  const float* img = (const float*)d_in[1];
  const float* kx  = (const float*)d_in[2];
  const float* ky  = (const float*)d_in[3];
  const float* kd  = (const float*)d_in[4];
  const float* kp  = (const float*)d_in[5];
  const float* k0  = (const float*)d_in[6];
  const float* k1  = (const float*)d_in[7];
  const float* k2  = (const float*)d_in[8];
  const float* sm  = (const float*)d_in[9];
  const float* kk  = (const float*)d_in[10];
  float* out = (float*)d_out;
  float* ws  = (float*)d_ws;

  precompute_kernels<<<1, 256, 0, stream>>>(kd, kp, k0, k1, k2, ws);
  dim3 grid(WW / T, HH / T, BB);
  forcing_main<<<grid, 256, 0, stream>>>(u, img, kx, ky, sm, kk, ws, out);
}

// Round 6
// 202.283 us; speedup vs baseline: 2.7155x; 1.2217x over previous
//
#include <hip/hip_runtime.h>
#include <cstddef>

#define HH 512
#define WW 512
#define BB 8
#define T  32

// ws layout (floats):
//   [0..72)    keff_edge  (3*3 spatial)*8ch   (depthwise∘pointwise, exact)
//   [72..193)  Keff11     11*11               (curve0∘curve1∘Σcurve2, composed)
//   [E0 .. )   e-map   [BB][512][520], x-padded 4+4 (stored col = x+4), zero pads
//   [K0 .. )   kp-map  [BB][512][520], kappa_pre*kk, same padding
#define MAPW  520
#define MAPB  (512 * MAPW)
#define E0    256
#define K0    (E0 + BB * MAPB)
#define WS_NEEDED_BYTES ((size_t)(K0 + BB * MAPB) * 4)

__global__ __launch_bounds__(256) void precompute_kernels(
    const float* __restrict__ kd,   // (3,3,1,8)
    const float* __restrict__ kp,   // (1,1,8,8)
    const float* __restrict__ k0,   // (5,5,1,8)
    const float* __restrict__ k1,   // (5,5,8,8)
    const float* __restrict__ k2,   // (3,3,8,16)
    float* __restrict__ ws) {
  __shared__ float k9[648];   // Keff9[(a*9+b)*8 + c1]  (curve0∘curve1)
  __shared__ float k2s[72];   // Σ_c2 k2[(t*3+v)*8+c1]
  const int tid = threadIdx.x;

  for (int idx = tid; idx < 72; idx += 256) {
    int c = idx & 7, pq = idx >> 3;
    float s = 0.f;
    for (int c0 = 0; c0 < 8; ++c0) s = fmaf(kd[pq * 8 + c0], kp[c0 * 8 + c], s);
    ws[idx] = s;
  }
  for (int idx = tid; idx < 72; idx += 256) {
    int c1 = idx & 7, tv = idx >> 3;
    float s = 0.f;
    for (int c2 = 0; c2 < 16; ++c2) s += k2[(tv * 8 + c1) * 16 + c2];
    k2s[idx] = s;
  }
  for (int idx = tid; idx < 648; idx += 256) {
    int c1 = idx & 7;
    int ab = idx >> 3;
    int a = ab / 9, b = ab % 9;
    float s = 0.f;
    int plo = a > 4 ? a - 4 : 0, phi = a < 4 ? a : 4;
    int qlo = b > 4 ? b - 4 : 0, qhi = b < 4 ? b : 4;
    for (int p = plo; p <= phi; ++p)
      for (int q = qlo; q <= qhi; ++q) {
        int r = a - p, sx = b - q;
        const float* k0p = &k0[(p * 5 + q) * 8];
        const float* k1p = &k1[((r * 5 + sx) * 8) * 8 + c1];
        for (int c0 = 0; c0 < 8; ++c0) s = fmaf(k0p[c0], k1p[c0 * 8], s);
      }
    k9[idx] = s;
  }
  __syncthreads();
  for (int idx = tid; idx < 121; idx += 256) {
    int A = idx / 11, B = idx % 11;
    float s = 0.f;
    int tlo = A > 8 ? A - 8 : 0, thi = A < 2 ? A : 2;
    int vlo = B > 8 ? B - 8 : 0, vhi = B < 2 ? B : 2;
    for (int t = tlo; t <= thi; ++t)
      for (int v = vlo; v <= vhi; ++v) {
        int a = A - t, b = B - v;
        for (int c1 = 0; c1 < 8; ++c1)
          s = fmaf(k9[(a * 9 + b) * 8 + c1], k2s[(t * 3 + v) * 8 + c1], s);
      }
    ws[72 + idx] = s;
  }
}

// ---------------- Split path: kernel A (edges + kappa_pre*kk -> maps) -------
// One 32x32 tile per 256-thread block; exactly one 4-px strip per thread for
// each of the two jobs -> zero intra-block imbalance. LDS only for u/img tiles.
// NOTE: ws and maps both point into d_ws (disjoint ranges) — no __restrict__.
__global__ __launch_bounds__(256) void kernelA(
    const float* __restrict__ u, const float* __restrict__ img,
    const float* __restrict__ kk, const float* ws,
    float* maps) {
  __shared__ float su[42 * 44];   // u tile, r=5 halo, stride 44 (aligned f4 rows)
  __shared__ float si[34 * 36];   // image tile, r=1 halo, stride 36

  const int bx = blockIdx.x * T, by = blockIdx.y * T, b = blockIdx.z;
  const int tid = threadIdx.x;
  const float* ub = u + (size_t)b * HH * WW;
  const float* ib = img + (size_t)b * HH * WW;

  for (int idx = tid; idx < 42 * 42; idx += 256) {
    int i = idx / 42, j = idx % 42;
    int gy = by - 5 + i, gx = bx - 5 + j;
    float v = 0.f;
    if ((unsigned)gy < HH && (unsigned)gx < WW) v = ub[gy * WW + gx];
    su[i * 44 + j] = v;
  }
  for (int idx = tid; idx < 34 * 34; idx += 256) {
    int i = idx / 34, j = idx % 34;
    int gy = by - 1 + i, gx = bx - 1 + j;
    float v = 0.f;
    if ((unsigned)gy < HH && (unsigned)gx < WW) v = ib[gy * WW + gx];
    si[i * 36 + j] = v;
  }
  __syncthreads();

  const int oy = tid >> 3, ox = (tid & 7) * 4;
  const int gy = by + oy, gx = bx + ox;

  // ---- edges strip (4 px): softsign(Σ_c relu(conv3x3(img, keff))) ----
  float acc[8][4];
  #pragma unroll
  for (int c = 0; c < 8; ++c)
    #pragma unroll
    for (int t = 0; t < 4; ++t) acc[c][t] = 0.f;
  #pragma unroll
  for (int p = 0; p < 3; ++p) {
    const float* srow = &si[(oy + p) * 36 + ox];
    float4 r4 = *reinterpret_cast<const float4*>(srow);
    float2 r2 = *reinterpret_cast<const float2*>(srow + 4);
    float r[6] = {r4.x, r4.y, r4.z, r4.w, r2.x, r2.y};
    #pragma unroll
    for (int q = 0; q < 3; ++q) {
      // wave-uniform address -> scalar load through K$
      float4 w0 = *reinterpret_cast<const float4*>(&ws[(p * 3 + q) * 8]);
      float4 w1 = *reinterpret_cast<const float4*>(&ws[(p * 3 + q) * 8 + 4]);
      #pragma unroll
      for (int t = 0; t < 4; ++t) {
        float v = r[q + t];
        acc[0][t] = fmaf(v, w0.x, acc[0][t]);
        acc[1][t] = fmaf(v, w0.y, acc[1][t]);
        acc[2][t] = fmaf(v, w0.z, acc[2][t]);
        acc[3][t] = fmaf(v, w0.w, acc[3][t]);
        acc[4][t] = fmaf(v, w1.x, acc[4][t]);
        acc[5][t] = fmaf(v, w1.y, acc[5][t]);
        acc[6][t] = fmaf(v, w1.z, acc[6][t]);
        acc[7][t] = fmaf(v, w1.w, acc[7][t]);
      }
    }
  }
  float ev[4];
  #pragma unroll
  for (int t = 0; t < 4; ++t) {
    float e = 0.f;
    #pragma unroll
    for (int c = 0; c < 8; ++c) e += fmaxf(acc[c][t], 0.f);
    ev[t] = e / (1.f + e);        // soft_sign, e >= 0
  }
  float* erow = maps + E0 + (size_t)b * MAPB + (size_t)gy * MAPW + 4 + gx;
  *reinterpret_cast<float4*>(erow) = make_float4(ev[0], ev[1], ev[2], ev[3]);

  // ---- kappa strip (4 px): conv11x11(u, Keff11) * kk ----
  float o0 = 0.f, o1 = 0.f, o2 = 0.f, o3 = 0.f;
  #pragma unroll
  for (int A = 0; A < 11; ++A) {
    const float* row = &su[(oy + A) * 44 + ox];
    float4 v0 = *reinterpret_cast<const float4*>(row);
    float4 v1 = *reinterpret_cast<const float4*>(row + 4);
    float4 v2 = *reinterpret_cast<const float4*>(row + 8);
    float2 v3 = *reinterpret_cast<const float2*>(row + 12);
    float r[14] = {v0.x, v0.y, v0.z, v0.w, v1.x, v1.y, v1.z, v1.w,
                   v2.x, v2.y, v2.z, v2.w, v3.x, v3.y};
    #pragma unroll
    for (int B2 = 0; B2 < 11; ++B2) {
      float w = ws[72 + A * 11 + B2];          // uniform -> s_load
      o0 = fmaf(r[B2],     w, o0);
      o1 = fmaf(r[B2 + 1], w, o1);
      o2 = fmaf(r[B2 + 2], w, o2);
      o3 = fmaf(r[B2 + 3], w, o3);
    }
  }
  float4 kkv = *reinterpret_cast<const float4*>(&kk[(size_t)gy * WW + gx]);
  float* krow = maps + K0 + (size_t)b * MAPB + (size_t)gy * MAPW + 4 + gx;
  *reinterpret_cast<float4*>(krow) =
      make_float4(o0 * kkv.x, o1 * kkv.y, o2 * kkv.z, o3 * kkv.w);

  // ---- zero the x-pad columns (tile-edge blocks only) ----
  if (bx == 0 && (tid & 7) == 0) {
    float4 z = make_float4(0.f, 0.f, 0.f, 0.f);
    *reinterpret_cast<float4*>(maps + E0 + (size_t)b * MAPB + (size_t)gy * MAPW) = z;
    *reinterpret_cast<float4*>(maps + K0 + (size_t)b * MAPB + (size_t)gy * MAPW) = z;
  }
  if (bx == WW - T && (tid & 7) == 7) {
    float4 z = make_float4(0.f, 0.f, 0.f, 0.f);
    *reinterpret_cast<float4*>(maps + E0 + (size_t)b * MAPB + (size_t)gy * MAPW + 516) = z;
    *reinterpret_cast<float4*>(maps + K0 + (size_t)b * MAPB + (size_t)gy * MAPW + 516) = z;
  }
}

// ---------------- Split path: kernel B (grads + smoother + combine) ---------
// LDS-free, barrier-free. 4-px strip per thread. Weights via uniform (scalar)
// loads; map windows via aligned global loads (x handled by map padding,
// y handled by clamp + multiply-by-mask).
__global__ __launch_bounds__(256) void kernelB(
    const float* __restrict__ u,
    const float* __restrict__ kx, const float* __restrict__ ky,
    const float* __restrict__ sm,
    const float* maps, float* __restrict__ out) {
  const int bx = blockIdx.x * T, by = blockIdx.y * T, b = blockIdx.z;
  const int tid = threadIdx.x;
  const int oy = tid >> 3, ox = (tid & 7) * 4;
  const int gy = by + oy, gx = bx + ox;

  const float* emap = maps + E0 + (size_t)b * MAPB;
  const float* kmap = maps + K0 + (size_t)b * MAPB;
  const float* ub   = u + (size_t)b * HH * WW;

  // ---- e window: rows gy-1..gy+1, cols gx-1..gx+4 ----
  float e[3][6];
  #pragma unroll
  for (int p = 0; p < 3; ++p) {
    int ry = gy - 1 + p;
    int rc = ry < 0 ? 0 : (ry > HH - 1 ? HH - 1 : ry);
    float m = (ry == rc) ? 1.f : 0.f;
    const float* row = emap + (size_t)rc * MAPW + 4 + gx;
    float2 a  = *reinterpret_cast<const float2*>(row - 2);
    float4 c4 = *reinterpret_cast<const float4*>(row);
    float  d  = row[4];
    e[p][0] = a.y * m;  e[p][1] = c4.x * m; e[p][2] = c4.y * m;
    e[p][3] = c4.z * m; e[p][4] = c4.w * m; e[p][5] = d * m;
  }

  // ---- grads: 32 channels x/y, relu-sum; weights via scalar loads ----
  float gxa[4] = {0.f, 0.f, 0.f, 0.f};
  float gya[4] = {0.f, 0.f, 0.f, 0.f};
  #pragma unroll
  for (int cq = 0; cq < 8; ++cq) {
    float sx[4][4], sy[4][4];
    #pragma unroll
    for (int cc = 0; cc < 4; ++cc)
      #pragma unroll
      for (int t = 0; t < 4; ++t) { sx[cc][t] = 0.f; sy[cc][t] = 0.f; }
    #pragma unroll
    for (int p = 0; p < 3; ++p)
      #pragma unroll
      for (int q = 0; q < 3; ++q) {
        float4 wx = *reinterpret_cast<const float4*>(&kx[(p * 3 + q) * 32 + cq * 4]);
        float4 wy = *reinterpret_cast<const float4*>(&ky[(p * 3 + q) * 32 + cq * 4]);
        #pragma unroll
        for (int t = 0; t < 4; ++t) {
          float evv = e[p][q + t];
          sx[0][t] = fmaf(evv, wx.x, sx[0][t]);
          sx[1][t] = fmaf(evv, wx.y, sx[1][t]);
          sx[2][t] = fmaf(evv, wx.z, sx[2][t]);
          sx[3][t] = fmaf(evv, wx.w, sx[3][t]);
          sy[0][t] = fmaf(evv, wy.x, sy[0][t]);
          sy[1][t] = fmaf(evv, wy.y, sy[1][t]);
          sy[2][t] = fmaf(evv, wy.z, sy[2][t]);
          sy[3][t] = fmaf(evv, wy.w, sy[3][t]);
        }
      }
    #pragma unroll
    for (int cc = 0; cc < 4; ++cc)
      #pragma unroll
      for (int t = 0; t < 4; ++t) {
        gxa[t] += fmaxf(sx[cc][t], 0.f);
        gya[t] += fmaxf(sy[cc][t], 0.f);
      }
  }

  // ---- smoother: 5x5 over kp map, rows gy-2..gy+2, cols gx-2..gx+5 ----
  float kap[4] = {0.f, 0.f, 0.f, 0.f};
  #pragma unroll
  for (int m5 = 0; m5 < 5; ++m5) {
    int ry = gy - 2 + m5;
    int rc = ry < 0 ? 0 : (ry > HH - 1 ? HH - 1 : ry);
    float msk = (ry == rc) ? 1.f : 0.f;
    const float* row = kmap + (size_t)rc * MAPW + 4 + gx;
    float2 a  = *reinterpret_cast<const float2*>(row - 2);
    float4 c4 = *reinterpret_cast<const float4*>(row);
    float2 d2 = *reinterpret_cast<const float2*>(row + 4);
    float r[8] = {a.x, a.y, c4.x, c4.y, c4.z, c4.w, d2.x, d2.y};
    #pragma unroll
    for (int n = 0; n < 5; ++n) {
      float w = sm[m5 * 5 + n] * msk;      // sm load is uniform -> scalar
      #pragma unroll
      for (int t = 0; t < 4; ++t) kap[t] = fmaf(r[t + n], w, kap[t]);
    }
  }

  // ---- u terms + combine ----
  const float* ur = ub + (size_t)gy * WW + gx;
  float4 uc4 = *reinterpret_cast<const float4*>(ur);
  int jm = gx > 0 ? -1 : 0;
  float ul = ur[jm];
  ul = gx > 0 ? ul : 0.f;
  int ryd = gy < HH - 1 ? gy + 1 : HH - 1;
  float md = gy < HH - 1 ? 1.f : 0.f;
  float4 ud4 = *reinterpret_cast<const float4*>(ub + (size_t)ryd * WW + gx);

  float uc[4]  = {uc4.x, uc4.y, uc4.z, uc4.w};
  float ulx[4] = {ul, uc4.x, uc4.y, uc4.z};
  float udn[4] = {ud4.x * md, ud4.y * md, ud4.z * md, ud4.w * md};

  float res[4];
  #pragma unroll
  for (int t = 0; t < 4; ++t) {
    float xp = uc[t] - ulx[t];               // u[y,x] - u[y,x-1]
    float yp = uc[t] - udn[t];               // u[y,x] - u[y+1,x]
    // fxn, fyn identically 0 (grads are sums of relus >= 0)
    res[t] = uc[t] + gxa[t] * xp + gya[t] * yp + e[1][1 + t] + kap[t];
  }
  *reinterpret_cast<float4*>(&out[((size_t)b * HH + gy) * WW + gx]) =
      make_float4(res[0], res[1], res[2], res[3]);
}

// ---------------- Fallback: R3 monolith (used if ws too small) --------------
__global__ __launch_bounds__(256) void forcing_main(
    const float* __restrict__ u, const float* __restrict__ img,
    const float* __restrict__ kx, const float* __restrict__ ky,
    const float* __restrict__ sm, const float* __restrict__ kk,
    const float* __restrict__ ws, float* __restrict__ out) {
  __shared__ float su[46][48];
  __shared__ float si[36][37];
  __shared__ float se[34][35];
  __shared__ float sk[36][37];
  __shared__ float w_edge[72];
  __shared__ float w_kx[288];
  __shared__ float w_ky[288];
  __shared__ float w_k11[124];
  __shared__ float w_sm[28];

  const int bx = blockIdx.x * T;
  const int by = blockIdx.y * T;
  const int b  = blockIdx.z;
  const int tid = threadIdx.x;
  const float* ub = u   + (size_t)b * HH * WW;
  const float* ib = img + (size_t)b * HH * WW;

  for (int i = tid; i < 72; i += 256)  w_edge[i] = ws[i];
  for (int i = tid; i < 121; i += 256) w_k11[i]  = ws[72 + i];
  for (int i = tid; i < 288; i += 256) { w_kx[i] = kx[i]; w_ky[i] = ky[i]; }
  if (tid < 25) w_sm[tid] = sm[tid];

  for (int idx = tid; idx < 46 * 46; idx += 256) {
    int i = idx / 46, j = idx % 46;
    int gy = by - 7 + i, gx = bx - 7 + j;
    float v = 0.f;
    if ((unsigned)gy < HH && (unsigned)gx < WW) v = ub[gy * WW + gx];
    su[i][j] = v;
  }
  for (int idx = tid; idx < 36 * 36; idx += 256) {
    int i = idx / 36, j = idx % 36;
    int gy = by - 2 + i, gx = bx - 2 + j;
    float v = 0.f;
    if ((unsigned)gy < HH && (unsigned)gx < WW) v = ib[gy * WW + gx];
    si[i][j] = v;
  }
  __syncthreads();

  for (int idx = tid; idx < 34 * 9; idx += 256) {
    int i = idx / 9, j0 = (idx % 9) * 4;
    float acc[8][4];
    #pragma unroll
    for (int c = 0; c < 8; ++c)
      #pragma unroll
      for (int t = 0; t < 4; ++t) acc[c][t] = 0.f;
    #pragma unroll
    for (int p = 0; p < 3; ++p) {
      float r[6];
      #pragma unroll
      for (int t = 0; t < 6; ++t) r[t] = si[i + p][j0 + t];
      #pragma unroll
      for (int q = 0; q < 3; ++q) {
        const float4 w0 = *reinterpret_cast<const float4*>(&w_edge[(p * 3 + q) * 8]);
        const float4 w1 = *reinterpret_cast<const float4*>(&w_edge[(p * 3 + q) * 8 + 4]);
        #pragma unroll
        for (int t = 0; t < 4; ++t) {
          float v = r[q + t];
          acc[0][t] = fmaf(v, w0.x, acc[0][t]);
          acc[1][t] = fmaf(v, w0.y, acc[1][t]);
          acc[2][t] = fmaf(v, w0.z, acc[2][t]);
          acc[3][t] = fmaf(v, w0.w, acc[3][t]);
          acc[4][t] = fmaf(v, w1.x, acc[4][t]);
          acc[5][t] = fmaf(v, w1.y, acc[5][t]);
          acc[6][t] = fmaf(v, w1.z, acc[6][t]);
          acc[7][t] = fmaf(v, w1.w, acc[7][t]);
        }
      }
    }
    int gy = by - 1 + i;
    #pragma unroll
    for (int t = 0; t < 4; ++t) {
      int j = j0 + t;
      if (j < 34) {
        int gx = bx - 1 + j;
        float val = 0.f;
        if ((unsigned)gy < HH && (unsigned)gx < WW) {
          float e = 0.f;
          #pragma unroll
          for (int c = 0; c < 8; ++c) e += fmaxf(acc[c][t], 0.f);
          val = e / (1.f + e);
        }
        se[i][j] = val;
      }
    }
  }

  for (int idx = tid; idx < 36 * 9; idx += 256) {
    int i = idx / 9, js = (idx % 9) * 4;
    float o0 = 0.f, o1 = 0.f, o2 = 0.f, o3 = 0.f;
    #pragma unroll
    for (int A = 0; A < 11; ++A) {
      const float* row = &su[i + A][js];
      float4 v0 = *reinterpret_cast<const float4*>(row);
      float4 v1 = *reinterpret_cast<const float4*>(row + 4);
      float4 v2 = *reinterpret_cast<const float4*>(row + 8);
      float r[14] = {v0.x, v0.y, v0.z, v0.w, v1.x, v1.y, v1.z, v1.w,
                     v2.x, v2.y, v2.z, v2.w, row[12], row[13]};
      #pragma unroll
      for (int B2 = 0; B2 < 11; ++B2) {
        float w = w_k11[A * 11 + B2];
        o0 = fmaf(r[B2],     w, o0);
        o1 = fmaf(r[B2 + 1], w, o1);
        o2 = fmaf(r[B2 + 2], w, o2);
        o3 = fmaf(r[B2 + 3], w, o3);
      }
    }
    int gy = by - 2 + i;
    float o[4] = {o0, o1, o2, o3};
    #pragma unroll
    for (int t = 0; t < 4; ++t) {
      int gx = bx - 2 + js + t;
      float val = 0.f;
      if ((unsigned)gy < HH && (unsigned)gx < WW) val = o[t] * kk[gy * WW + gx];
      sk[i][js + t] = val;
    }
  }
  __syncthreads();

  {
    const int oy = tid >> 3;
    const int ox = (tid & 7) * 4;
    const int gy = by + oy;
    const int gx = bx + ox;

    float e[3][6];
    #pragma unroll
    for (int p = 0; p < 3; ++p)
      #pragma unroll
      for (int t = 0; t < 6; ++t) e[p][t] = se[oy + p][ox + t];

    const float4* wx4 = reinterpret_cast<const float4*>(w_kx);
    const float4* wy4 = reinterpret_cast<const float4*>(w_ky);

    float gxa[4] = {0.f, 0.f, 0.f, 0.f};
    float gya[4] = {0.f, 0.f, 0.f, 0.f};
    #pragma unroll
    for (int cq = 0; cq < 8; ++cq) {
      float sx[4][4], sy[4][4];
      #pragma unroll
      for (int cc = 0; cc < 4; ++cc)
        #pragma unroll
        for (int t = 0; t < 4; ++t) { sx[cc][t] = 0.f; sy[cc][t] = 0.f; }
      #pragma unroll
      for (int p = 0; p < 3; ++p)
        #pragma unroll
        for (int q = 0; q < 3; ++q) {
          float4 wx = wx4[(p * 3 + q) * 8 + cq];
          float4 wy = wy4[(p * 3 + q) * 8 + cq];
          #pragma unroll
          for (int t = 0; t < 4; ++t) {
            float evv = e[p][q + t];
            sx[0][t] = fmaf(evv, wx.x, sx[0][t]);
            sx[1][t] = fmaf(evv, wx.y, sx[1][t]);
            sx[2][t] = fmaf(evv, wx.z, sx[2][t]);
            sx[3][t] = fmaf(evv, wx.w, sx[3][t]);
            sy[0][t] = fmaf(evv, wy.x, sy[0][t]);
            sy[1][t] = fmaf(evv, wy.y, sy[1][t]);
            sy[2][t] = fmaf(evv, wy.z, sy[2][t]);
            sy[3][t] = fmaf(evv, wy.w, sy[3][t]);
          }
        }
      #pragma unroll
      for (int cc = 0; cc < 4; ++cc)
        #pragma unroll
        for (int t = 0; t < 4; ++t) {
          gxa[t] += fmaxf(sx[cc][t], 0.f);
          gya[t] += fmaxf(sy[cc][t], 0.f);
        }
    }

    float res[4];
    #pragma unroll
    for (int t = 0; t < 4; ++t) {
      float kap = 0.f;
      #pragma unroll
      for (int m = 0; m < 5; ++m)
        #pragma unroll
        for (int n = 0; n < 5; ++n)
          kap = fmaf(sk[oy + m][ox + t + n], w_sm[m * 5 + n], kap);

      float uc = su[oy + 7][ox + 7 + t];
      float xp = uc - su[oy + 7][ox + 6 + t];
      float yp = uc - su[oy + 8][ox + 7 + t];
      float ec = se[oy + 1][ox + 1 + t];
      res[t] = uc + gxa[t] * xp + gya[t] * yp + ec + kap;
    }

    float4 r4 = make_float4(res[0], res[1], res[2], res[3]);
    *reinterpret_cast<float4*>(&out[((size_t)b * HH + gy) * WW + gx]) = r4;
  }
}

extern "C" void kernel_launch(void* const* d_in, const int* in_sizes, int n_in,
                              void* d_out, int out_size, void* d_ws, size_t ws_size,
                              hipStream_t stream) {
  const float* u   = (const float*)d_in[0];
  const float* img = (const float*)d_in[1];
  const float* kx  = (const float*)d_in[2];
  const float* ky  = (const float*)d_in[3];
  const float* kd  = (const float*)d_in[4];
  const float* kp  = (const float*)d_in[5];
  const float* k0  = (const float*)d_in[6];
  const float* k1  = (const float*)d_in[7];
  const float* k2  = (const float*)d_in[8];
  const float* sm  = (const float*)d_in[9];
  const float* kk  = (const float*)d_in[10];
  float* out = (float*)d_out;
  float* ws  = (float*)d_ws;

  precompute_kernels<<<1, 256, 0, stream>>>(kd, kp, k0, k1, k2, ws);
  dim3 grid(WW / T, HH / T, BB);
  if (ws != nullptr && ws_size >= WS_NEEDED_BYTES) {
    kernelA<<<grid, 256, 0, stream>>>(u, img, kk, ws, ws);
    kernelB<<<grid, 256, 0, stream>>>(u, kx, ky, sm, ws, out);
  } else {
    forcing_main<<<grid, 256, 0, stream>>>(u, img, kx, ky, sm, kk, ws, out);
  }
}

// Round 9
// 180.423 us; speedup vs baseline: 3.0445x; 1.1212x over previous
//
#include <hip/hip_runtime.h>
#include <cstddef>

#define HH 512
#define WW 512
#define BB 8
#define T  32

// ws layout (floats):
//   [0..72)      keff_edge  (3*3)*8ch
//   [72..193)    Keff11     11*11
//   [256..1280)  F-bank: 4 N-tiles x 64 lanes x 8 bf16 = 2048 bf16 = 1024 FLOATS
//                (R7 bug: E0=768 overlapped this -> garbage. E0 must be >= 1280.)
//   [E0..)       e-map   [BB][512][520] fp32, x-padded 4+4 (stored col = x+4), zero pads
//   [K0..)       kp-map  [BB][512][520] kappa_pre*kk, same padding
#define F0    256
#define E0    1280
#define MAPW  520
#define MAPB  (512 * MAPW)
#define K0    (E0 + BB * MAPB)
#define WS_NEEDED_BYTES ((size_t)(K0 + BB * MAPB) * 4)

typedef __attribute__((ext_vector_type(8))) short short8;
typedef __attribute__((ext_vector_type(4))) float float4v;

__device__ inline unsigned short f2bf(float f) {   // fp32 -> bf16 RNE
  unsigned u = __builtin_bit_cast(unsigned, f);
  unsigned r = (u + 0x7FFFu + ((u >> 16) & 1u)) >> 16;
  return (unsigned short)r;
}

__global__ __launch_bounds__(256) void precompute_kernels(
    const float* __restrict__ kd,   // (3,3,1,8)
    const float* __restrict__ kp,   // (1,1,8,8)
    const float* __restrict__ k0,   // (5,5,1,8)
    const float* __restrict__ k1,   // (5,5,8,8)
    const float* __restrict__ k2,   // (3,3,8,16)
    const float* __restrict__ kx,   // (3,3,1,32)
    const float* __restrict__ ky,   // (3,3,1,32)
    float* __restrict__ ws) {
  __shared__ float k9[648];
  __shared__ float k2s[72];
  const int tid = threadIdx.x;

  for (int idx = tid; idx < 72; idx += 256) {
    int c = idx & 7, pq = idx >> 3;
    float s = 0.f;
    for (int c0 = 0; c0 < 8; ++c0) s = fmaf(kd[pq * 8 + c0], kp[c0 * 8 + c], s);
    ws[idx] = s;
  }
  for (int idx = tid; idx < 72; idx += 256) {
    int c1 = idx & 7, tv = idx >> 3;
    float s = 0.f;
    for (int c2 = 0; c2 < 16; ++c2) s += k2[(tv * 8 + c1) * 16 + c2];
    k2s[idx] = s;
  }
  for (int idx = tid; idx < 648; idx += 256) {
    int c1 = idx & 7;
    int ab = idx >> 3;
    int a = ab / 9, b = ab % 9;
    float s = 0.f;
    int plo = a > 4 ? a - 4 : 0, phi = a < 4 ? a : 4;
    int qlo = b > 4 ? b - 4 : 0, qhi = b < 4 ? b : 4;
    for (int p = plo; p <= phi; ++p)
      for (int q = qlo; q <= qhi; ++q) {
        int r = a - p, sx = b - q;
        const float* k0p = &k0[(p * 5 + q) * 8];
        const float* k1p = &k1[((r * 5 + sx) * 8) * 8 + c1];
        for (int c0 = 0; c0 < 8; ++c0) s = fmaf(k0p[c0], k1p[c0 * 8], s);
      }
    k9[idx] = s;
  }
  // F-bank: tile nt (n = nt*16 + lane&15), lane ln, j -> k = (ln>>4)*8+j
  // F[k][n] = (n<32 ? kx : ky)[k*32 + n%32], zero for k>=9.  storage (nt*64+ln)*8+j
  for (int idx = tid; idx < 2048; idx += 256) {
    int nt = idx >> 9, ln = (idx >> 3) & 63, j = idx & 7;
    int k = (ln >> 4) * 8 + j;
    int n = nt * 16 + (ln & 15);
    float v = 0.f;
    if (k < 9) v = (n < 32) ? kx[k * 32 + n] : ky[k * 32 + (n - 32)];
    ((unsigned short*)ws)[F0 * 2 + idx] = f2bf(v);
  }
  __syncthreads();
  for (int idx = tid; idx < 121; idx += 256) {
    int A = idx / 11, B = idx % 11;
    float s = 0.f;
    int tlo = A > 8 ? A - 8 : 0, thi = A < 2 ? A : 2;
    int vlo = B > 8 ? B - 8 : 0, vhi = B < 2 ? B : 2;
    for (int t = tlo; t <= thi; ++t)
      for (int v = vlo; v <= vhi; ++v) {
        int a = A - t, b = B - v;
        for (int c1 = 0; c1 < 8; ++c1)
          s = fmaf(k9[(a * 9 + b) * 8 + c1], k2s[(t * 3 + v) * 8 + c1], s);
      }
    ws[72 + idx] = s;
  }
}

// ---------------- kernel A (edges + kappa_pre*kk -> maps) — unchanged R6 ----
__global__ __launch_bounds__(256) void kernelA(
    const float* __restrict__ u, const float* __restrict__ img,
    const float* __restrict__ kk, const float* ws,
    float* maps) {
  __shared__ float su[42 * 44];
  __shared__ float si[34 * 36];

  const int bx = blockIdx.x * T, by = blockIdx.y * T, b = blockIdx.z;
  const int tid = threadIdx.x;
  const float* ub = u + (size_t)b * HH * WW;
  const float* ib = img + (size_t)b * HH * WW;

  for (int idx = tid; idx < 42 * 42; idx += 256) {
    int i = idx / 42, j = idx % 42;
    int gy = by - 5 + i, gx = bx - 5 + j;
    float v = 0.f;
    if ((unsigned)gy < HH && (unsigned)gx < WW) v = ub[gy * WW + gx];
    su[i * 44 + j] = v;
  }
  for (int idx = tid; idx < 34 * 34; idx += 256) {
    int i = idx / 34, j = idx % 34;
    int gy = by - 1 + i, gx = bx - 1 + j;
    float v = 0.f;
    if ((unsigned)gy < HH && (unsigned)gx < WW) v = ib[gy * WW + gx];
    si[i * 36 + j] = v;
  }
  __syncthreads();

  const int oy = tid >> 3, ox = (tid & 7) * 4;
  const int gy = by + oy, gx = bx + ox;

  float acc[8][4];
  #pragma unroll
  for (int c = 0; c < 8; ++c)
    #pragma unroll
    for (int t = 0; t < 4; ++t) acc[c][t] = 0.f;
  #pragma unroll
  for (int p = 0; p < 3; ++p) {
    const float* srow = &si[(oy + p) * 36 + ox];
    float4 r4 = *reinterpret_cast<const float4*>(srow);
    float2 r2 = *reinterpret_cast<const float2*>(srow + 4);
    float r[6] = {r4.x, r4.y, r4.z, r4.w, r2.x, r2.y};
    #pragma unroll
    for (int q = 0; q < 3; ++q) {
      float4 w0 = *reinterpret_cast<const float4*>(&ws[(p * 3 + q) * 8]);
      float4 w1 = *reinterpret_cast<const float4*>(&ws[(p * 3 + q) * 8 + 4]);
      #pragma unroll
      for (int t = 0; t < 4; ++t) {
        float v = r[q + t];
        acc[0][t] = fmaf(v, w0.x, acc[0][t]);
        acc[1][t] = fmaf(v, w0.y, acc[1][t]);
        acc[2][t] = fmaf(v, w0.z, acc[2][t]);
        acc[3][t] = fmaf(v, w0.w, acc[3][t]);
        acc[4][t] = fmaf(v, w1.x, acc[4][t]);
        acc[5][t] = fmaf(v, w1.y, acc[5][t]);
        acc[6][t] = fmaf(v, w1.z, acc[6][t]);
        acc[7][t] = fmaf(v, w1.w, acc[7][t]);
      }
    }
  }
  float ev[4];
  #pragma unroll
  for (int t = 0; t < 4; ++t) {
    float e = 0.f;
    #pragma unroll
    for (int c = 0; c < 8; ++c) e += fmaxf(acc[c][t], 0.f);
    ev[t] = e / (1.f + e);
  }
  float* erow = maps + E0 + (size_t)b * MAPB + (size_t)gy * MAPW + 4 + gx;
  *reinterpret_cast<float4*>(erow) = make_float4(ev[0], ev[1], ev[2], ev[3]);

  float o0 = 0.f, o1 = 0.f, o2 = 0.f, o3 = 0.f;
  #pragma unroll
  for (int A = 0; A < 11; ++A) {
    const float* row = &su[(oy + A) * 44 + ox];
    float4 v0 = *reinterpret_cast<const float4*>(row);
    float4 v1 = *reinterpret_cast<const float4*>(row + 4);
    float4 v2 = *reinterpret_cast<const float4*>(row + 8);
    float2 v3 = *reinterpret_cast<const float2*>(row + 12);
    float r[14] = {v0.x, v0.y, v0.z, v0.w, v1.x, v1.y, v1.z, v1.w,
                   v2.x, v2.y, v2.z, v2.w, v3.x, v3.y};
    #pragma unroll
    for (int B2 = 0; B2 < 11; ++B2) {
      float w = ws[72 + A * 11 + B2];
      o0 = fmaf(r[B2],     w, o0);
      o1 = fmaf(r[B2 + 1], w, o1);
      o2 = fmaf(r[B2 + 2], w, o2);
      o3 = fmaf(r[B2 + 3], w, o3);
    }
  }
  float4 kkv = *reinterpret_cast<const float4*>(&kk[(size_t)gy * WW + gx]);
  float* krow = maps + K0 + (size_t)b * MAPB + (size_t)gy * MAPW + 4 + gx;
  *reinterpret_cast<float4*>(krow) =
      make_float4(o0 * kkv.x, o1 * kkv.y, o2 * kkv.z, o3 * kkv.w);

  if (bx == 0 && (tid & 7) == 0) {
    float4 z = make_float4(0.f, 0.f, 0.f, 0.f);
    *reinterpret_cast<float4*>(maps + E0 + (size_t)b * MAPB + (size_t)gy * MAPW) = z;
    *reinterpret_cast<float4*>(maps + K0 + (size_t)b * MAPB + (size_t)gy * MAPW) = z;
  }
  if (bx == WW - T && (tid & 7) == 7) {
    float4 z = make_float4(0.f, 0.f, 0.f, 0.f);
    *reinterpret_cast<float4*>(maps + E0 + (size_t)b * MAPB + (size_t)gy * MAPW + 516) = z;
    *reinterpret_cast<float4*>(maps + K0 + (size_t)b * MAPB + (size_t)gy * MAPW + 516) = z;
  }
}

// ---------------- kernel B v2: MFMA grad bank + smoother + combine ----------
__global__ __launch_bounds__(256) void kernelB(
    const float* __restrict__ u,
    const float* __restrict__ sm,
    const float* maps, float* __restrict__ out) {
  __shared__ unsigned short sbf[34 * 36];  // e tile (halo 1), bf16
  __shared__ float sgx[32 * 32];
  __shared__ float sgy[32 * 32];

  const int bx = blockIdx.x * T, by = blockIdx.y * T, b = blockIdx.z;
  const int tid = threadIdx.x;
  const float* emap = maps + E0 + (size_t)b * MAPB;
  const float* kmap = maps + K0 + (size_t)b * MAPB;
  const float* ub   = u + (size_t)b * HH * WW;

  // phase 1: stage e tile (rows by-1..by+32, cols bx-1..bx+32) as bf16.
  // x via map padding (stored col bx+3+j in [3,516] always valid); y clamp+mask.
  for (int idx = tid; idx < 34 * 34; idx += 256) {
    int i = idx / 34, j = idx % 34;
    int ry = by - 1 + i;
    int rc = ry < 0 ? 0 : (ry > HH - 1 ? HH - 1 : ry);
    float msk = (ry == rc) ? 1.f : 0.f;
    float v = emap[(size_t)rc * MAPW + bx + 3 + j] * msk;
    sbf[i * 36 + j] = f2bf(v);
  }

  const int lane = tid & 63;
  const int wv   = tid >> 6;
  const int q    = lane >> 4;
  const int m    = lane & 15;

  // B-frags: 4 N-tiles of the filter bank (pre-swizzled by precompute)
  short8 bfr[4];
  {
    const unsigned short* F = ((const unsigned short*)maps) + F0 * 2;
    #pragma unroll
    for (int nt = 0; nt < 4; ++nt)
      bfr[nt] = *reinterpret_cast<const short8*>(F + (nt * 64 + lane) * 8);
  }

  // per-lane tap offsets: A[m][k] = e34[r + k/3][xl + k%3], k = q*8+j
  int  off[8];
  bool act[8];
  #pragma unroll
  for (int j = 0; j < 8; ++j) {
    int k = q * 8 + j;
    act[j] = (k < 9);
    int kk = act[j] ? k : 0;
    off[j] = (kk / 3) * 36 + (kk % 3);
  }

  __syncthreads();

  // phase 2: wave wv covers rows 8*wv..8*wv+7, both 16-px halves
  for (int gi = 0; gi < 16; ++gi) {
    int g = wv * 16 + gi;
    int r = g >> 1, h = (g & 1) * 16;
    int base = r * 36 + h + m;

    short8 av = (short8)0;
    #pragma unroll
    for (int j = 0; j < 8; ++j)
      if (act[j]) av[j] = (short)sbf[base + off[j]];

    float4v c0 = {0.f, 0.f, 0.f, 0.f}, c1 = c0, c2 = c0, c3 = c0;
    c0 = __builtin_amdgcn_mfma_f32_16x16x32_bf16(av, bfr[0], c0, 0, 0, 0);
    c1 = __builtin_amdgcn_mfma_f32_16x16x32_bf16(av, bfr[1], c1, 0, 0, 0);
    c2 = __builtin_amdgcn_mfma_f32_16x16x32_bf16(av, bfr[2], c2, 0, 0, 0);
    c3 = __builtin_amdgcn_mfma_f32_16x16x32_bf16(av, bfr[3], c3, 0, 0, 0);

    // relu + pair-sum (x = tiles 0,1 ; y = tiles 2,3), then 16-lane col sum
    float rx[4], ry[4];
    #pragma unroll
    for (int i = 0; i < 4; ++i) {
      rx[i] = fmaxf(c0[i], 0.f) + fmaxf(c1[i], 0.f);
      ry[i] = fmaxf(c2[i], 0.f) + fmaxf(c3[i], 0.f);
    }
    #pragma unroll
    for (int s = 1; s < 16; s <<= 1) {
      #pragma unroll
      for (int i = 0; i < 4; ++i) {
        rx[i] += __shfl_xor(rx[i], s);
        ry[i] += __shfl_xor(ry[i], s);
      }
    }
    // C row = q*4 + reg = px index within group; lane col 0 of each quad writes
    if (m == 0) {
      int px = h + q * 4;
      *reinterpret_cast<float4*>(&sgx[r * 32 + px]) =
          make_float4(rx[0], rx[1], rx[2], rx[3]);
      *reinterpret_cast<float4*>(&sgy[r * 32 + px]) =
          make_float4(ry[0], ry[1], ry[2], ry[3]);
    }
  }
  __syncthreads();

  // phase 3: per-thread 4-px strip — smoother + FD + combine
  {
    const int oy = tid >> 3, ox = (tid & 7) * 4;
    const int gy = by + oy, gx = bx + ox;

    float4 gx4 = *reinterpret_cast<const float4*>(&sgx[oy * 32 + ox]);
    float4 gy4 = *reinterpret_cast<const float4*>(&sgy[oy * 32 + ox]);
    float gxa[4] = {gx4.x, gx4.y, gx4.z, gx4.w};
    float gya[4] = {gy4.x, gy4.y, gy4.z, gy4.w};

    float4 ec4 = *reinterpret_cast<const float4*>(&emap[(size_t)gy * MAPW + 4 + gx]);
    float ec[4] = {ec4.x, ec4.y, ec4.z, ec4.w};

    float kap[4] = {0.f, 0.f, 0.f, 0.f};
    #pragma unroll
    for (int m5 = 0; m5 < 5; ++m5) {
      int ry = gy - 2 + m5;
      int rc = ry < 0 ? 0 : (ry > HH - 1 ? HH - 1 : ry);
      float msk = (ry == rc) ? 1.f : 0.f;
      const float* row = kmap + (size_t)rc * MAPW + 4 + gx;
      float2 a  = *reinterpret_cast<const float2*>(row - 2);
      float4 c4 = *reinterpret_cast<const float4*>(row);
      float2 d2 = *reinterpret_cast<const float2*>(row + 4);
      float r[8] = {a.x, a.y, c4.x, c4.y, c4.z, c4.w, d2.x, d2.y};
      #pragma unroll
      for (int n = 0; n < 5; ++n) {
        float w = sm[m5 * 5 + n] * msk;
        #pragma unroll
        for (int t = 0; t < 4; ++t) kap[t] = fmaf(r[t + n], w, kap[t]);
      }
    }

    const float* ur = ub + (size_t)gy * WW + gx;
    float4 uc4 = *reinterpret_cast<const float4*>(ur);
    int jm = gx > 0 ? -1 : 0;
    float ul = ur[jm];
    ul = gx > 0 ? ul : 0.f;
    int ryd = gy < HH - 1 ? gy + 1 : HH - 1;
    float md = gy < HH - 1 ? 1.f : 0.f;
    float4 ud4 = *reinterpret_cast<const float4*>(ub + (size_t)ryd * WW + gx);

    float uc[4]  = {uc4.x, uc4.y, uc4.z, uc4.w};
    float ulx[4] = {ul, uc4.x, uc4.y, uc4.z};
    float udn[4] = {ud4.x * md, ud4.y * md, ud4.z * md, ud4.w * md};

    float res[4];
    #pragma unroll
    for (int t = 0; t < 4; ++t) {
      float xp = uc[t] - ulx[t];
      float yp = uc[t] - udn[t];
      res[t] = uc[t] + gxa[t] * xp + gya[t] * yp + ec[t] + kap[t];
    }
    *reinterpret_cast<float4*>(&out[((size_t)b * HH + gy) * WW + gx]) =
        make_float4(res[0], res[1], res[2], res[3]);
  }
}

// ---------------- Fallback: R3 monolith (used if ws too small) --------------
__global__ __launch_bounds__(256) void forcing_main(
    const float* __restrict__ u, const float* __restrict__ img,
    const float* __restrict__ kx, const float* __restrict__ ky,
    const float* __restrict__ sm, const float* __restrict__ kk,
    const float* __restrict__ ws, float* __restrict__ out) {
  __shared__ float su[46][48];
  __shared__ float si[36][37];
  __shared__ float se[34][35];
  __shared__ float sk[36][37];
  __shared__ float w_edge[72];
  __shared__ float w_kx[288];
  __shared__ float w_ky[288];
  __shared__ float w_k11[124];
  __shared__ float w_sm[28];

  const int bx = blockIdx.x * T;
  const int by = blockIdx.y * T;
  const int b  = blockIdx.z;
  const int tid = threadIdx.x;
  const float* ub = u   + (size_t)b * HH * WW;
  const float* ib = img + (size_t)b * HH * WW;

  for (int i = tid; i < 72; i += 256)  w_edge[i] = ws[i];
  for (int i = tid; i < 121; i += 256) w_k11[i]  = ws[72 + i];
  for (int i = tid; i < 288; i += 256) { w_kx[i] = kx[i]; w_ky[i] = ky[i]; }
  if (tid < 25) w_sm[tid] = sm[tid];

  for (int idx = tid; idx < 46 * 46; idx += 256) {
    int i = idx / 46, j = idx % 46;
    int gy = by - 7 + i, gx = bx - 7 + j;
    float v = 0.f;
    if ((unsigned)gy < HH && (unsigned)gx < WW) v = ub[gy * WW + gx];
    su[i][j] = v;
  }
  for (int idx = tid; idx < 36 * 36; idx += 256) {
    int i = idx / 36, j = idx % 36;
    int gy = by - 2 + i, gx = bx - 2 + j;
    float v = 0.f;
    if ((unsigned)gy < HH && (unsigned)gx < WW) v = ib[gy * WW + gx];
    si[i][j] = v;
  }
  __syncthreads();

  for (int idx = tid; idx < 34 * 9; idx += 256) {
    int i = idx / 9, j0 = (idx % 9) * 4;
    float acc[8][4];
    #pragma unroll
    for (int c = 0; c < 8; ++c)
      #pragma unroll
      for (int t = 0; t < 4; ++t) acc[c][t] = 0.f;
    #pragma unroll
    for (int p = 0; p < 3; ++p) {
      float r[6];
      #pragma unroll
      for (int t = 0; t < 6; ++t) r[t] = si[i + p][j0 + t];
      #pragma unroll
      for (int q = 0; q < 3; ++q) {
        const float4 w0 = *reinterpret_cast<const float4*>(&w_edge[(p * 3 + q) * 8]);
        const float4 w1 = *reinterpret_cast<const float4*>(&w_edge[(p * 3 + q) * 8 + 4]);
        #pragma unroll
        for (int t = 0; t < 4; ++t) {
          float v = r[q + t];
          acc[0][t] = fmaf(v, w0.x, acc[0][t]);
          acc[1][t] = fmaf(v, w0.y, acc[1][t]);
          acc[2][t] = fmaf(v, w0.z, acc[2][t]);
          acc[3][t] = fmaf(v, w0.w, acc[3][t]);
          acc[4][t] = fmaf(v, w1.x, acc[4][t]);
          acc[5][t] = fmaf(v, w1.y, acc[5][t]);
          acc[6][t] = fmaf(v, w1.z, acc[6][t]);
          acc[7][t] = fmaf(v, w1.w, acc[7][t]);
        }
      }
    }
    int gy = by - 1 + i;
    #pragma unroll
    for (int t = 0; t < 4; ++t) {
      int j = j0 + t;
      if (j < 34) {
        int gx = bx - 1 + j;
        float val = 0.f;
        if ((unsigned)gy < HH && (unsigned)gx < WW) {
          float e = 0.f;
          #pragma unroll
          for (int c = 0; c < 8; ++c) e += fmaxf(acc[c][t], 0.f);
          val = e / (1.f + e);
        }
        se[i][j] = val;
      }
    }
  }

  for (int idx = tid; idx < 36 * 9; idx += 256) {
    int i = idx / 9, js = (idx % 9) * 4;
    float o0 = 0.f, o1 = 0.f, o2 = 0.f, o3 = 0.f;
    #pragma unroll
    for (int A = 0; A < 11; ++A) {
      const float* row = &su[i + A][js];
      float4 v0 = *reinterpret_cast<const float4*>(row);
      float4 v1 = *reinterpret_cast<const float4*>(row + 4);
      float4 v2 = *reinterpret_cast<const float4*>(row + 8);
      float r[14] = {v0.x, v0.y, v0.z, v0.w, v1.x, v1.y, v1.z, v1.w,
                     v2.x, v2.y, v2.z, v2.w, row[12], row[13]};
      #pragma unroll
      for (int B2 = 0; B2 < 11; ++B2) {
        float w = w_k11[A * 11 + B2];
        o0 = fmaf(r[B2],     w, o0);
        o1 = fmaf(r[B2 + 1], w, o1);
        o2 = fmaf(r[B2 + 2], w, o2);
        o3 = fmaf(r[B2 + 3], w, o3);
      }
    }
    int gy = by - 2 + i;
    float o[4] = {o0, o1, o2, o3};
    #pragma unroll
    for (int t = 0; t < 4; ++t) {
      int gx = bx - 2 + js + t;
      float val = 0.f;
      if ((unsigned)gy < HH && (unsigned)gx < WW) val = o[t] * kk[gy * WW + gx];
      sk[i][js + t] = val;
    }
  }
  __syncthreads();

  {
    const int oy = tid >> 3;
    const int ox = (tid & 7) * 4;
    const int gy = by + oy;
    const int gx = bx + ox;

    float e[3][6];
    #pragma unroll
    for (int p = 0; p < 3; ++p)
      #pragma unroll
      for (int t = 0; t < 6; ++t) e[p][t] = se[oy + p][ox + t];

    const float4* wx4 = reinterpret_cast<const float4*>(w_kx);
    const float4* wy4 = reinterpret_cast<const float4*>(w_ky);

    float gxa[4] = {0.f, 0.f, 0.f, 0.f};
    float gya[4] = {0.f, 0.f, 0.f, 0.f};
    #pragma unroll
    for (int cq = 0; cq < 8; ++cq) {
      float sx[4][4], sy[4][4];
      #pragma unroll
      for (int cc = 0; cc < 4; ++cc)
        #pragma unroll
        for (int t = 0; t < 4; ++t) { sx[cc][t] = 0.f; sy[cc][t] = 0.f; }
      #pragma unroll
      for (int p = 0; p < 3; ++p)
        #pragma unroll
        for (int q = 0; q < 3; ++q) {
          float4 wx = wx4[(p * 3 + q) * 8 + cq];
          float4 wy = wy4[(p * 3 + q) * 8 + cq];
          #pragma unroll
          for (int t = 0; t < 4; ++t) {
            float evv = e[p][q + t];
            sx[0][t] = fmaf(evv, wx.x, sx[0][t]);
            sx[1][t] = fmaf(evv, wx.y, sx[1][t]);
            sx[2][t] = fmaf(evv, wx.z, sx[2][t]);
            sx[3][t] = fmaf(evv, wx.w, sx[3][t]);
            sy[0][t] = fmaf(evv, wy.x, sy[0][t]);
            sy[1][t] = fmaf(evv, wy.y, sy[1][t]);
            sy[2][t] = fmaf(evv, wy.z, sy[2][t]);
            sy[3][t] = fmaf(evv, wy.w, sy[3][t]);
          }
        }
      #pragma unroll
      for (int cc = 0; cc < 4; ++cc)
        #pragma unroll
        for (int t = 0; t < 4; ++t) {
          gxa[t] += fmaxf(sx[cc][t], 0.f);
          gya[t] += fmaxf(sy[cc][t], 0.f);
        }
    }

    float res[4];
    #pragma unroll
    for (int t = 0; t < 4; ++t) {
      float kap = 0.f;
      #pragma unroll
      for (int m = 0; m < 5; ++m)
        #pragma unroll
        for (int n = 0; n < 5; ++n)
          kap = fmaf(sk[oy + m][ox + t + n], w_sm[m * 5 + n], kap);

      float uc = su[oy + 7][ox + 7 + t];
      float xp = uc - su[oy + 7][ox + 6 + t];
      float yp = uc - su[oy + 8][ox + 7 + t];
      float ec = se[oy + 1][ox + 1 + t];
      res[t] = uc + gxa[t] * xp + gya[t] * yp + ec + kap;
    }

    float4 r4 = make_float4(res[0], res[1], res[2], res[3]);
    *reinterpret_cast<float4*>(&out[((size_t)b * HH + gy) * WW + gx]) = r4;
  }
}

extern "C" void kernel_launch(void* const* d_in, const int* in_sizes, int n_in,
                              void* d_out, int out_size, void* d_ws, size_t ws_size,
                              hipStream_t stream) {
  const float* u   = (const float*)d_in[0];
  const float* img = (const float*)d_in[1];
  const float* kx  = (const float*)d_in[2];
  const float* ky  = (const float*)d_in[3];
  const float* kd  = (const float*)d_in[4];
  const float* kp  = (const float*)d_in[5];
  const float* k0  = (const float*)d_in[6];
  const float* k1  = (const float*)d_in[7];
  const float* k2  = (const float*)d_in[8];
  const float* sm  = (const float*)d_in[9];
  const float* kk  = (const float*)d_in[10];
  float* out = (float*)d_out;
  float* ws  = (float*)d_ws;

  precompute_kernels<<<1, 256, 0, stream>>>(kd, kp, k0, k1, k2, kx, ky, ws);
  dim3 grid(WW / T, HH / T, BB);
  if (ws != nullptr && ws_size >= WS_NEEDED_BYTES) {
    kernelA<<<grid, 256, 0, stream>>>(u, img, kk, ws, ws);
    kernelB<<<grid, 256, 0, stream>>>(u, sm, ws, out);
  } else {
    forcing_main<<<grid, 256, 0, stream>>>(u, img, kx, ky, sm, kk, ws, out);
  }
}

// Round 10
// 154.163 us; speedup vs baseline: 3.5631x; 1.1703x over previous
//
#include <hip/hip_runtime.h>
#include <cstddef>

#define HH 512
#define WW 512
#define BB 8
#define T  32

// ws layout (floats):
//   [0..72)      keff_edge  (3*3)*8ch
//   [72..193)    Keff11     11*11
//   [256..1280)  F-bank: 4 tiles x 64 lanes x 8 bf16 = 2048 bf16 = 1024 floats
//                frag[lane][j] = filter(tile*16 + lane&15), tap k=(lane>>4)*8+j
//                (identical index map for A- and B-frag roles; HW-verified R9)
//   [E0..)       e-map   [BB][512][520] fp32, x-padded 4+4 (stored col = x+4), zero pads
//   [K0..)       kp-map  [BB][512][520] kappa_pre*kk, same padding
#define F0    256
#define E0    1280
#define MAPW  520
#define MAPB  (512 * MAPW)
#define K0    (E0 + BB * MAPB)
#define WS_NEEDED_BYTES ((size_t)(K0 + BB * MAPB) * 4)

typedef __attribute__((ext_vector_type(8))) short short8;
typedef __attribute__((ext_vector_type(4))) float float4v;

__device__ inline unsigned short f2bf(float f) {   // fp32 -> bf16 RNE
  unsigned u = __builtin_bit_cast(unsigned, f);
  unsigned r = (u + 0x7FFFu + ((u >> 16) & 1u)) >> 16;
  return (unsigned short)r;
}

__global__ __launch_bounds__(256) void precompute_kernels(
    const float* __restrict__ kd,   // (3,3,1,8)
    const float* __restrict__ kp,   // (1,1,8,8)
    const float* __restrict__ k0,   // (5,5,1,8)
    const float* __restrict__ k1,   // (5,5,8,8)
    const float* __restrict__ k2,   // (3,3,8,16)
    const float* __restrict__ kx,   // (3,3,1,32)
    const float* __restrict__ ky,   // (3,3,1,32)
    float* __restrict__ ws) {
  __shared__ float k9[648];
  __shared__ float k2s[72];
  const int tid = threadIdx.x;

  for (int idx = tid; idx < 72; idx += 256) {
    int c = idx & 7, pq = idx >> 3;
    float s = 0.f;
    for (int c0 = 0; c0 < 8; ++c0) s = fmaf(kd[pq * 8 + c0], kp[c0 * 8 + c], s);
    ws[idx] = s;
  }
  for (int idx = tid; idx < 72; idx += 256) {
    int c1 = idx & 7, tv = idx >> 3;
    float s = 0.f;
    for (int c2 = 0; c2 < 16; ++c2) s += k2[(tv * 8 + c1) * 16 + c2];
    k2s[idx] = s;
  }
  for (int idx = tid; idx < 648; idx += 256) {
    int c1 = idx & 7;
    int ab = idx >> 3;
    int a = ab / 9, b = ab % 9;
    float s = 0.f;
    int plo = a > 4 ? a - 4 : 0, phi = a < 4 ? a : 4;
    int qlo = b > 4 ? b - 4 : 0, qhi = b < 4 ? b : 4;
    for (int p = plo; p <= phi; ++p)
      for (int q = qlo; q <= qhi; ++q) {
        int r = a - p, sx = b - q;
        const float* k0p = &k0[(p * 5 + q) * 8];
        const float* k1p = &k1[((r * 5 + sx) * 8) * 8 + c1];
        for (int c0 = 0; c0 < 8; ++c0) s = fmaf(k0p[c0], k1p[c0 * 8], s);
      }
    k9[idx] = s;
  }
  // F-bank
  for (int idx = tid; idx < 2048; idx += 256) {
    int nt = idx >> 9, ln = (idx >> 3) & 63, j = idx & 7;
    int k = (ln >> 4) * 8 + j;
    int n = nt * 16 + (ln & 15);
    float v = 0.f;
    if (k < 9) v = (n < 32) ? kx[k * 32 + n] : ky[k * 32 + (n - 32)];
    ((unsigned short*)ws)[F0 * 2 + idx] = f2bf(v);
  }
  __syncthreads();
  for (int idx = tid; idx < 121; idx += 256) {
    int A = idx / 11, B = idx % 11;
    float s = 0.f;
    int tlo = A > 8 ? A - 8 : 0, thi = A < 2 ? A : 2;
    int vlo = B > 8 ? B - 8 : 0, vhi = B < 2 ? B : 2;
    for (int t = tlo; t <= thi; ++t)
      for (int v = vlo; v <= vhi; ++v) {
        int a = A - t, b = B - v;
        for (int c1 = 0; c1 < 8; ++c1)
          s = fmaf(k9[(a * 9 + b) * 8 + c1], k2s[(t * 3 + v) * 8 + c1], s);
      }
    ws[72 + idx] = s;
  }
}

// ---------------- kernel A (edges + kappa_pre*kk -> maps) — unchanged R6 ----
__global__ __launch_bounds__(256) void kernelA(
    const float* __restrict__ u, const float* __restrict__ img,
    const float* __restrict__ kk, const float* ws,
    float* maps) {
  __shared__ float su[42 * 44];
  __shared__ float si[34 * 36];

  const int bx = blockIdx.x * T, by = blockIdx.y * T, b = blockIdx.z;
  const int tid = threadIdx.x;
  const float* ub = u + (size_t)b * HH * WW;
  const float* ib = img + (size_t)b * HH * WW;

  for (int idx = tid; idx < 42 * 42; idx += 256) {
    int i = idx / 42, j = idx % 42;
    int gy = by - 5 + i, gx = bx - 5 + j;
    float v = 0.f;
    if ((unsigned)gy < HH && (unsigned)gx < WW) v = ub[gy * WW + gx];
    su[i * 44 + j] = v;
  }
  for (int idx = tid; idx < 34 * 34; idx += 256) {
    int i = idx / 34, j = idx % 34;
    int gy = by - 1 + i, gx = bx - 1 + j;
    float v = 0.f;
    if ((unsigned)gy < HH && (unsigned)gx < WW) v = ib[gy * WW + gx];
    si[i * 36 + j] = v;
  }
  __syncthreads();

  const int oy = tid >> 3, ox = (tid & 7) * 4;
  const int gy = by + oy, gx = bx + ox;

  float acc[8][4];
  #pragma unroll
  for (int c = 0; c < 8; ++c)
    #pragma unroll
    for (int t = 0; t < 4; ++t) acc[c][t] = 0.f;
  #pragma unroll
  for (int p = 0; p < 3; ++p) {
    const float* srow = &si[(oy + p) * 36 + ox];
    float4 r4 = *reinterpret_cast<const float4*>(srow);
    float2 r2 = *reinterpret_cast<const float2*>(srow + 4);
    float r[6] = {r4.x, r4.y, r4.z, r4.w, r2.x, r2.y};
    #pragma unroll
    for (int q = 0; q < 3; ++q) {
      float4 w0 = *reinterpret_cast<const float4*>(&ws[(p * 3 + q) * 8]);
      float4 w1 = *reinterpret_cast<const float4*>(&ws[(p * 3 + q) * 8 + 4]);
      #pragma unroll
      for (int t = 0; t < 4; ++t) {
        float v = r[q + t];
        acc[0][t] = fmaf(v, w0.x, acc[0][t]);
        acc[1][t] = fmaf(v, w0.y, acc[1][t]);
        acc[2][t] = fmaf(v, w0.z, acc[2][t]);
        acc[3][t] = fmaf(v, w0.w, acc[3][t]);
        acc[4][t] = fmaf(v, w1.x, acc[4][t]);
        acc[5][t] = fmaf(v, w1.y, acc[5][t]);
        acc[6][t] = fmaf(v, w1.z, acc[6][t]);
        acc[7][t] = fmaf(v, w1.w, acc[7][t]);
      }
    }
  }
  float ev[4];
  #pragma unroll
  for (int t = 0; t < 4; ++t) {
    float e = 0.f;
    #pragma unroll
    for (int c = 0; c < 8; ++c) e += fmaxf(acc[c][t], 0.f);
    ev[t] = e / (1.f + e);
  }
  float* erow = maps + E0 + (size_t)b * MAPB + (size_t)gy * MAPW + 4 + gx;
  *reinterpret_cast<float4*>(erow) = make_float4(ev[0], ev[1], ev[2], ev[3]);

  float o0 = 0.f, o1 = 0.f, o2 = 0.f, o3 = 0.f;
  #pragma unroll
  for (int A = 0; A < 11; ++A) {
    const float* row = &su[(oy + A) * 44 + ox];
    float4 v0 = *reinterpret_cast<const float4*>(row);
    float4 v1 = *reinterpret_cast<const float4*>(row + 4);
    float4 v2 = *reinterpret_cast<const float4*>(row + 8);
    float2 v3 = *reinterpret_cast<const float2*>(row + 12);
    float r[14] = {v0.x, v0.y, v0.z, v0.w, v1.x, v1.y, v1.z, v1.w,
                   v2.x, v2.y, v2.z, v2.w, v3.x, v3.y};
    #pragma unroll
    for (int B2 = 0; B2 < 11; ++B2) {
      float w = ws[72 + A * 11 + B2];
      o0 = fmaf(r[B2],     w, o0);
      o1 = fmaf(r[B2 + 1], w, o1);
      o2 = fmaf(r[B2 + 2], w, o2);
      o3 = fmaf(r[B2 + 3], w, o3);
    }
  }
  float4 kkv = *reinterpret_cast<const float4*>(&kk[(size_t)gy * WW + gx]);
  float* krow = maps + K0 + (size_t)b * MAPB + (size_t)gy * MAPW + 4 + gx;
  *reinterpret_cast<float4*>(krow) =
      make_float4(o0 * kkv.x, o1 * kkv.y, o2 * kkv.z, o3 * kkv.w);

  if (bx == 0 && (tid & 7) == 0) {
    float4 z = make_float4(0.f, 0.f, 0.f, 0.f);
    *reinterpret_cast<float4*>(maps + E0 + (size_t)b * MAPB + (size_t)gy * MAPW) = z;
    *reinterpret_cast<float4*>(maps + K0 + (size_t)b * MAPB + (size_t)gy * MAPW) = z;
  }
  if (bx == WW - T && (tid & 7) == 7) {
    float4 z = make_float4(0.f, 0.f, 0.f, 0.f);
    *reinterpret_cast<float4*>(maps + E0 + (size_t)b * MAPB + (size_t)gy * MAPW + 516) = z;
    *reinterpret_cast<float4*>(maps + K0 + (size_t)b * MAPB + (size_t)gy * MAPW + 516) = z;
  }
}

// ---------------- kernel B v3: transposed MFMA (filters=A, pixels=B) --------
// C[row=filter][col=pixel]; filter-sum = 8 in-lane relu-adds + 2 shuffles
// (xor16, xor32) instead of a 4-step 16-lane butterfly over 8 values.
// Pixel taps rolled in registers from global emap (vmem pipe) — no LDS staging.
__global__ __launch_bounds__(256) void kernelB(
    const float* __restrict__ u,
    const float* __restrict__ sm,
    const float* maps, float* __restrict__ out) {
  __shared__ float sgx[32 * 32];
  __shared__ float sgy[32 * 32];

  const int bx = blockIdx.x * T, by = blockIdx.y * T, b = blockIdx.z;
  const int tid = threadIdx.x;
  const float* emap = maps + E0 + (size_t)b * MAPB;
  const float* kmap = maps + K0 + (size_t)b * MAPB;
  const float* ub   = u + (size_t)b * HH * WW;

  const int lane = tid & 63;
  const int wv   = tid >> 6;
  const int q    = lane >> 4;
  const int m    = lane & 15;

  // A-frags: filters from F-bank (A-frag index map == B-frag index map)
  short8 afr[4];
  {
    const unsigned short* F = ((const unsigned short*)maps) + F0 * 2;
    #pragma unroll
    for (int t = 0; t < 4; ++t)
      afr[t] = *reinterpret_cast<const short8*>(F + (t * 64 + lane) * 8);
  }

  const int gy0 = by + wv * 8;   // first pixel row handled by this wave

  #pragma unroll
  for (int h = 0; h < 32; h += 16) {
    const int gxl = bx + h + m;                 // this lane's pixel column
    const float* colp = emap + 4 + gxl - 1;     // x-padded: always valid

    // rolling 3x3 tap window W[d*3+c] = e[gy-1+d][gxl-1+c], bf16
    unsigned short W[9];
    #pragma unroll
    for (int d = 0; d < 3; ++d) {
      int ry = gy0 - 1 + d;
      int rc = ry < 0 ? 0 : (ry > HH - 1 ? HH - 1 : ry);
      float msk = (ry == rc) ? 1.f : 0.f;
      const float* rp = colp + (size_t)rc * MAPW;
      W[3 * d + 0] = f2bf(rp[0] * msk);
      W[3 * d + 1] = f2bf(rp[1] * msk);
      W[3 * d + 2] = f2bf(rp[2] * msk);
    }

    #pragma unroll
    for (int r = 0; r < 8; ++r) {
      // B-frag: B[k=q*8+j][n=pixel m]. q0: taps 0-7; q1: tap 8; q2/3: zero.
      short8 bv = (short8)0;
      if (q == 0) {
        #pragma unroll
        for (int j = 0; j < 8; ++j) bv[j] = (short)W[j];
      } else if (q == 1) {
        bv[0] = (short)W[8];
      }

      float4v c0 = {0.f, 0.f, 0.f, 0.f}, c1 = c0, c2 = c0, c3 = c0;
      c0 = __builtin_amdgcn_mfma_f32_16x16x32_bf16(afr[0], bv, c0, 0, 0, 0);
      c1 = __builtin_amdgcn_mfma_f32_16x16x32_bf16(afr[1], bv, c1, 0, 0, 0);
      c2 = __builtin_amdgcn_mfma_f32_16x16x32_bf16(afr[2], bv, c2, 0, 0, 0);
      c3 = __builtin_amdgcn_mfma_f32_16x16x32_bf16(afr[3], bv, c3, 0, 0, 0);

      // in-lane: relu + sum over this quad's 4 filter-rows, tiles paired
      float rx = 0.f, ry = 0.f;
      #pragma unroll
      for (int i = 0; i < 4; ++i) {
        rx += fmaxf(c0[i], 0.f) + fmaxf(c1[i], 0.f);
        ry += fmaxf(c2[i], 0.f) + fmaxf(c3[i], 0.f);
      }
      // cross-quad: 2 shuffles each
      rx += __shfl_xor(rx, 16); rx += __shfl_xor(rx, 32);
      ry += __shfl_xor(ry, 16); ry += __shfl_xor(ry, 32);

      if (q == 0) {
        sgx[(wv * 8 + r) * 32 + h + m] = rx;
        sgy[(wv * 8 + r) * 32 + h + m] = ry;
      }

      // roll window down one pixel row
      if (r < 7) {
        #pragma unroll
        for (int t = 0; t < 6; ++t) W[t] = W[t + 3];
        int ryn = gy0 + r + 2;
        int rcn = ryn < 0 ? 0 : (ryn > HH - 1 ? HH - 1 : ryn);
        float msk = (ryn == rcn) ? 1.f : 0.f;
        const float* rp = colp + (size_t)rcn * MAPW;
        W[6] = f2bf(rp[0] * msk);
        W[7] = f2bf(rp[1] * msk);
        W[8] = f2bf(rp[2] * msk);
      }
    }
  }
  __syncthreads();

  // phase 3: per-thread 4-px strip — smoother + FD + combine
  {
    const int oy = tid >> 3, ox = (tid & 7) * 4;
    const int gy = by + oy, gx = bx + ox;

    float4 gx4 = *reinterpret_cast<const float4*>(&sgx[oy * 32 + ox]);
    float4 gy4 = *reinterpret_cast<const float4*>(&sgy[oy * 32 + ox]);
    float gxa[4] = {gx4.x, gx4.y, gx4.z, gx4.w};
    float gya[4] = {gy4.x, gy4.y, gy4.z, gy4.w};

    float4 ec4 = *reinterpret_cast<const float4*>(&emap[(size_t)gy * MAPW + 4 + gx]);
    float ec[4] = {ec4.x, ec4.y, ec4.z, ec4.w};

    float kap[4] = {0.f, 0.f, 0.f, 0.f};
    #pragma unroll
    for (int m5 = 0; m5 < 5; ++m5) {
      int ry = gy - 2 + m5;
      int rc = ry < 0 ? 0 : (ry > HH - 1 ? HH - 1 : ry);
      float msk = (ry == rc) ? 1.f : 0.f;
      const float* row = kmap + (size_t)rc * MAPW + 4 + gx;
      float2 a  = *reinterpret_cast<const float2*>(row - 2);
      float4 c4 = *reinterpret_cast<const float4*>(row);
      float2 d2 = *reinterpret_cast<const float2*>(row + 4);
      float r[8] = {a.x, a.y, c4.x, c4.y, c4.z, c4.w, d2.x, d2.y};
      #pragma unroll
      for (int n = 0; n < 5; ++n) {
        float w = sm[m5 * 5 + n] * msk;
        #pragma unroll
        for (int t = 0; t < 4; ++t) kap[t] = fmaf(r[t + n], w, kap[t]);
      }
    }

    const float* ur = ub + (size_t)gy * WW + gx;
    float4 uc4 = *reinterpret_cast<const float4*>(ur);
    int jm = gx > 0 ? -1 : 0;
    float ul = ur[jm];
    ul = gx > 0 ? ul : 0.f;
    int ryd = gy < HH - 1 ? gy + 1 : HH - 1;
    float md = gy < HH - 1 ? 1.f : 0.f;
    float4 ud4 = *reinterpret_cast<const float4*>(ub + (size_t)ryd * WW + gx);

    float uc[4]  = {uc4.x, uc4.y, uc4.z, uc4.w};
    float ulx[4] = {ul, uc4.x, uc4.y, uc4.z};
    float udn[4] = {ud4.x * md, ud4.y * md, ud4.z * md, ud4.w * md};

    float res[4];
    #pragma unroll
    for (int t = 0; t < 4; ++t) {
      float xp = uc[t] - ulx[t];
      float yp = uc[t] - udn[t];
      res[t] = uc[t] + gxa[t] * xp + gya[t] * yp + ec[t] + kap[t];
    }
    *reinterpret_cast<float4*>(&out[((size_t)b * HH + gy) * WW + gx]) =
        make_float4(res[0], res[1], res[2], res[3]);
  }
}

// ---------------- Fallback: R3 monolith (used if ws too small) --------------
__global__ __launch_bounds__(256) void forcing_main(
    const float* __restrict__ u, const float* __restrict__ img,
    const float* __restrict__ kx, const float* __restrict__ ky,
    const float* __restrict__ sm, const float* __restrict__ kk,
    const float* __restrict__ ws, float* __restrict__ out) {
  __shared__ float su[46][48];
  __shared__ float si[36][37];
  __shared__ float se[34][35];
  __shared__ float sk[36][37];
  __shared__ float w_edge[72];
  __shared__ float w_kx[288];
  __shared__ float w_ky[288];
  __shared__ float w_k11[124];
  __shared__ float w_sm[28];

  const int bx = blockIdx.x * T;
  const int by = blockIdx.y * T;
  const int b  = blockIdx.z;
  const int tid = threadIdx.x;
  const float* ub = u   + (size_t)b * HH * WW;
  const float* ib = img + (size_t)b * HH * WW;

  for (int i = tid; i < 72; i += 256)  w_edge[i] = ws[i];
  for (int i = tid; i < 121; i += 256) w_k11[i]  = ws[72 + i];
  for (int i = tid; i < 288; i += 256) { w_kx[i] = kx[i]; w_ky[i] = ky[i]; }
  if (tid < 25) w_sm[tid] = sm[tid];

  for (int idx = tid; idx < 46 * 46; idx += 256) {
    int i = idx / 46, j = idx % 46;
    int gy = by - 7 + i, gx = bx - 7 + j;
    float v = 0.f;
    if ((unsigned)gy < HH && (unsigned)gx < WW) v = ub[gy * WW + gx];
    su[i][j] = v;
  }
  for (int idx = tid; idx < 36 * 36; idx += 256) {
    int i = idx / 36, j = idx % 36;
    int gy = by - 2 + i, gx = bx - 2 + j;
    float v = 0.f;
    if ((unsigned)gy < HH && (unsigned)gx < WW) v = ib[gy * WW + gx];
    si[i][j] = v;
  }
  __syncthreads();

  for (int idx = tid; idx < 34 * 9; idx += 256) {
    int i = idx / 9, j0 = (idx % 9) * 4;
    float acc[8][4];
    #pragma unroll
    for (int c = 0; c < 8; ++c)
      #pragma unroll
      for (int t = 0; t < 4; ++t) acc[c][t] = 0.f;
    #pragma unroll
    for (int p = 0; p < 3; ++p) {
      float r[6];
      #pragma unroll
      for (int t = 0; t < 6; ++t) r[t] = si[i + p][j0 + t];
      #pragma unroll
      for (int q = 0; q < 3; ++q) {
        const float4 w0 = *reinterpret_cast<const float4*>(&w_edge[(p * 3 + q) * 8]);
        const float4 w1 = *reinterpret_cast<const float4*>(&w_edge[(p * 3 + q) * 8 + 4]);
        #pragma unroll
        for (int t = 0; t < 4; ++t) {
          float v = r[q + t];
          acc[0][t] = fmaf(v, w0.x, acc[0][t]);
          acc[1][t] = fmaf(v, w0.y, acc[1][t]);
          acc[2][t] = fmaf(v, w0.z, acc[2][t]);
          acc[3][t] = fmaf(v, w0.w, acc[3][t]);
          acc[4][t] = fmaf(v, w1.x, acc[4][t]);
          acc[5][t] = fmaf(v, w1.y, acc[5][t]);
          acc[6][t] = fmaf(v, w1.z, acc[6][t]);
          acc[7][t] = fmaf(v, w1.w, acc[7][t]);
        }
      }
    }
    int gy = by - 1 + i;
    #pragma unroll
    for (int t = 0; t < 4; ++t) {
      int j = j0 + t;
      if (j < 34) {
        int gx = bx - 1 + j;
        float val = 0.f;
        if ((unsigned)gy < HH && (unsigned)gx < WW) {
          float e = 0.f;
          #pragma unroll
          for (int c = 0; c < 8; ++c) e += fmaxf(acc[c][t], 0.f);
          val = e / (1.f + e);
        }
        se[i][j] = val;
      }
    }
  }

  for (int idx = tid; idx < 36 * 9; idx += 256) {
    int i = idx / 9, js = (idx % 9) * 4;
    float o0 = 0.f, o1 = 0.f, o2 = 0.f, o3 = 0.f;
    #pragma unroll
    for (int A = 0; A < 11; ++A) {
      const float* row = &su[i + A][js];
      float4 v0 = *reinterpret_cast<const float4*>(row);
      float4 v1 = *reinterpret_cast<const float4*>(row + 4);
      float4 v2 = *reinterpret_cast<const float4*>(row + 8);
      float r[14] = {v0.x, v0.y, v0.z, v0.w, v1.x, v1.y, v1.z, v1.w,
                     v2.x, v2.y, v2.z, v2.w, row[12], row[13]};
      #pragma unroll
      for (int B2 = 0; B2 < 11; ++B2) {
        float w = w_k11[A * 11 + B2];
        o0 = fmaf(r[B2],     w, o0);
        o1 = fmaf(r[B2 + 1], w, o1);
        o2 = fmaf(r[B2 + 2], w, o2);
        o3 = fmaf(r[B2 + 3], w, o3);
      }
    }
    int gy = by - 2 + i;
    float o[4] = {o0, o1, o2, o3};
    #pragma unroll
    for (int t = 0; t < 4; ++t) {
      int gx = bx - 2 + js + t;
      float val = 0.f;
      if ((unsigned)gy < HH && (unsigned)gx < WW) val = o[t] * kk[gy * WW + gx];
      sk[i][js + t] = val;
    }
  }
  __syncthreads();

  {
    const int oy = tid >> 3;
    const int ox = (tid & 7) * 4;
    const int gy = by + oy;
    const int gx = bx + ox;

    float e[3][6];
    #pragma unroll
    for (int p = 0; p < 3; ++p)
      #pragma unroll
      for (int t = 0; t < 6; ++t) e[p][t] = se[oy + p][ox + t];

    const float4* wx4 = reinterpret_cast<const float4*>(w_kx);
    const float4* wy4 = reinterpret_cast<const float4*>(w_ky);

    float gxa[4] = {0.f, 0.f, 0.f, 0.f};
    float gya[4] = {0.f, 0.f, 0.f, 0.f};
    #pragma unroll
    for (int cq = 0; cq < 8; ++cq) {
      float sx[4][4], sy[4][4];
      #pragma unroll
      for (int cc = 0; cc < 4; ++cc)
        #pragma unroll
        for (int t = 0; t < 4; ++t) { sx[cc][t] = 0.f; sy[cc][t] = 0.f; }
      #pragma unroll
      for (int p = 0; p < 3; ++p)
        #pragma unroll
        for (int q = 0; q < 3; ++q) {
          float4 wx = wx4[(p * 3 + q) * 8 + cq];
          float4 wy = wy4[(p * 3 + q) * 8 + cq];
          #pragma unroll
          for (int t = 0; t < 4; ++t) {
            float evv = e[p][q + t];
            sx[0][t] = fmaf(evv, wx.x, sx[0][t]);
            sx[1][t] = fmaf(evv, wx.y, sx[1][t]);
            sx[2][t] = fmaf(evv, wx.z, sx[2][t]);
            sx[3][t] = fmaf(evv, wx.w, sx[3][t]);
            sy[0][t] = fmaf(evv, wy.x, sy[0][t]);
            sy[1][t] = fmaf(evv, wy.y, sy[1][t]);
            sy[2][t] = fmaf(evv, wy.z, sy[2][t]);
            sy[3][t] = fmaf(evv, wy.w, sy[3][t]);
          }
        }
      #pragma unroll
      for (int cc = 0; cc < 4; ++cc)
        #pragma unroll
        for (int t = 0; t < 4; ++t) {
          gxa[t] += fmaxf(sx[cc][t], 0.f);
          gya[t] += fmaxf(sy[cc][t], 0.f);
        }
    }

    float res[4];
    #pragma unroll
    for (int t = 0; t < 4; ++t) {
      float kap = 0.f;
      #pragma unroll
      for (int m = 0; m < 5; ++m)
        #pragma unroll
        for (int n = 0; n < 5; ++n)
          kap = fmaf(sk[oy + m][ox + t + n], w_sm[m * 5 + n], kap);

      float uc = su[oy + 7][ox + 7 + t];
      float xp = uc - su[oy + 7][ox + 6 + t];
      float yp = uc - su[oy + 8][ox + 7 + t];
      float ec = se[oy + 1][ox + 1 + t];
      res[t] = uc + gxa[t] * xp + gya[t] * yp + ec + kap;
    }

    float4 r4 = make_float4(res[0], res[1], res[2], res[3]);
    *reinterpret_cast<float4*>(&out[((size_t)b * HH + gy) * WW + gx]) = r4;
  }
}

extern "C" void kernel_launch(void* const* d_in, const int* in_sizes, int n_in,
                              void* d_out, int out_size, void* d_ws, size_t ws_size,
                              hipStream_t stream) {
  const float* u   = (const float*)d_in[0];
  const float* img = (const float*)d_in[1];
  const float* kx  = (const float*)d_in[2];
  const float* ky  = (const float*)d_in[3];
  const float* kd  = (const float*)d_in[4];
  const float* kp  = (const float*)d_in[5];
  const float* k0  = (const float*)d_in[6];
  const float* k1  = (const float*)d_in[7];
  const float* k2  = (const float*)d_in[8];
  const float* sm  = (const float*)d_in[9];
  const float* kk  = (const float*)d_in[10];
  float* out = (float*)d_out;
  float* ws  = (float*)d_ws;

  precompute_kernels<<<1, 256, 0, stream>>>(kd, kp, k0, k1, k2, kx, ky, ws);
  dim3 grid(WW / T, HH / T, BB);
  if (ws != nullptr && ws_size >= WS_NEEDED_BYTES) {
    kernelA<<<grid, 256, 0, stream>>>(u, img, kk, ws, ws);
    kernelB<<<grid, 256, 0, stream>>>(u, sm, ws, out);
  } else {
    forcing_main<<<grid, 256, 0, stream>>>(u, img, kx, ky, sm, kk, ws, out);
  }
}

// Round 11
// 143.781 us; speedup vs baseline: 3.8204x; 1.0722x over previous
//
#include <hip/hip_runtime.h>
#include <cstddef>

#define HH 512
#define WW 512
#define BB 8
#define T  32

// ws layout (floats):
//   [0..72)      keff_edge  (3*3)*8ch
//   [72..193)    Keff11     11*11
//   [256..1280)  F-bank (grad filters): 4 tiles x 64 lanes x 8 bf16
//   [1280..4096) KT-bank (kappa Toeplitz): 11 b x 64 lanes x 8 bf16 = 5632 bf16
//                KT_b[m=lane&15][k=(lane>>4)*8+j] = Keff11[k-m-3][b] if 0<=k-m-3<11
//   [E0..)       e-map   [BB][512][520] fp32, x-padded 4+4 (stored col = x+4)
//   [K0..)       kp-map  [BB][512][520] kappa_pre*kk, same padding
#define F0    256
#define KT0   1280
#define E0    4096
#define MAPW  520
#define MAPB  (512 * MAPW)
#define K0    (E0 + BB * MAPB)
#define WS_NEEDED_BYTES ((size_t)(K0 + BB * MAPB) * 4)

typedef __attribute__((ext_vector_type(8))) short short8;
typedef __attribute__((ext_vector_type(4))) float float4v;

__device__ inline unsigned short f2bf(float f) {   // fp32 -> bf16 RNE
  unsigned u = __builtin_bit_cast(unsigned, f);
  unsigned r = (u + 0x7FFFu + ((u >> 16) & 1u)) >> 16;
  return (unsigned short)r;
}

__global__ __launch_bounds__(256) void precompute_kernels(
    const float* __restrict__ kd,   // (3,3,1,8)
    const float* __restrict__ kp,   // (1,1,8,8)
    const float* __restrict__ k0,   // (5,5,1,8)
    const float* __restrict__ k1,   // (5,5,8,8)
    const float* __restrict__ k2,   // (3,3,8,16)
    const float* __restrict__ kx,   // (3,3,1,32)
    const float* __restrict__ ky,   // (3,3,1,32)
    float* __restrict__ ws) {
  __shared__ float k9[648];
  __shared__ float k2s[72];
  __shared__ float kef[121];
  const int tid = threadIdx.x;

  for (int idx = tid; idx < 72; idx += 256) {
    int c = idx & 7, pq = idx >> 3;
    float s = 0.f;
    for (int c0 = 0; c0 < 8; ++c0) s = fmaf(kd[pq * 8 + c0], kp[c0 * 8 + c], s);
    ws[idx] = s;
  }
  for (int idx = tid; idx < 72; idx += 256) {
    int c1 = idx & 7, tv = idx >> 3;
    float s = 0.f;
    for (int c2 = 0; c2 < 16; ++c2) s += k2[(tv * 8 + c1) * 16 + c2];
    k2s[idx] = s;
  }
  for (int idx = tid; idx < 648; idx += 256) {
    int c1 = idx & 7;
    int ab = idx >> 3;
    int a = ab / 9, b = ab % 9;
    float s = 0.f;
    int plo = a > 4 ? a - 4 : 0, phi = a < 4 ? a : 4;
    int qlo = b > 4 ? b - 4 : 0, qhi = b < 4 ? b : 4;
    for (int p = plo; p <= phi; ++p)
      for (int q = qlo; q <= qhi; ++q) {
        int r = a - p, sx = b - q;
        const float* k0p = &k0[(p * 5 + q) * 8];
        const float* k1p = &k1[((r * 5 + sx) * 8) * 8 + c1];
        for (int c0 = 0; c0 < 8; ++c0) s = fmaf(k0p[c0], k1p[c0 * 8], s);
      }
    k9[idx] = s;
  }
  // F-bank (grad filters)
  for (int idx = tid; idx < 2048; idx += 256) {
    int nt = idx >> 9, ln = (idx >> 3) & 63, j = idx & 7;
    int k = (ln >> 4) * 8 + j;
    int n = nt * 16 + (ln & 15);
    float v = 0.f;
    if (k < 9) v = (n < 32) ? kx[k * 32 + n] : ky[k * 32 + (n - 32)];
    ((unsigned short*)ws)[F0 * 2 + idx] = f2bf(v);
  }
  __syncthreads();
  for (int idx = tid; idx < 121; idx += 256) {
    int A = idx / 11, B = idx % 11;
    float s = 0.f;
    int tlo = A > 8 ? A - 8 : 0, thi = A < 2 ? A : 2;
    int vlo = B > 8 ? B - 8 : 0, vhi = B < 2 ? B : 2;
    for (int t = tlo; t <= thi; ++t)
      for (int v = vlo; v <= vhi; ++v) {
        int a = A - t, b = B - v;
        for (int c1 = 0; c1 < 8; ++c1)
          s = fmaf(k9[(a * 9 + b) * 8 + c1], k2s[(t * 3 + v) * 8 + c1], s);
      }
    ws[72 + idx] = s;
    kef[idx] = s;
  }
  __syncthreads();
  // KT-bank: kappa Toeplitz A-frags (bf16)
  for (int idx = tid; idx < 5632; idx += 256) {
    int b = idx >> 9, ln = (idx >> 3) & 63, j = idx & 7;
    int m = ln & 15;
    int k = (ln >> 4) * 8 + j;
    int a = k - m - 3;
    float v = ((unsigned)a < 11u) ? kef[a * 11 + b] : 0.f;
    ((unsigned short*)ws)[KT0 * 2 + idx] = f2bf(v);
  }
}

// ---------------- kernel A v2: edges (VALU) + kappa (Toeplitz MFMA) --------
__global__ __launch_bounds__(256) void kernelA(
    const float* __restrict__ u, const float* __restrict__ img,
    const float* __restrict__ kk, const float* ws,
    float* maps) {
  __shared__ unsigned short suT[42 * 56];  // u tile TRANSPOSED bf16: [col][row]
                                           // cols bx-5..bx+36, rows by-8..by+39
  __shared__ float si[34 * 36];            // image tile, r=1 halo

  const int bx = blockIdx.x * T, by = blockIdx.y * T, b = blockIdx.z;
  const int tid = threadIdx.x;
  const float* ub = u + (size_t)b * HH * WW;
  const float* ib = img + (size_t)b * HH * WW;

  // ---- stage suT (bf16, transposed) + si ----
  for (int idx = tid; idx < 48 * 42; idx += 256) {
    int r = idx / 42, c = idx % 42;          // global-coalesced reads per row
    int gy = by - 8 + r, gx = bx - 5 + c;
    float v = 0.f;
    if ((unsigned)gy < HH && (unsigned)gx < WW) v = ub[gy * WW + gx];
    suT[c * 56 + r] = f2bf(v);
  }
  for (int idx = tid; idx < 34 * 34; idx += 256) {
    int i = idx / 34, j = idx % 34;
    int gy = by - 1 + i, gx = bx - 1 + j;
    float v = 0.f;
    if ((unsigned)gy < HH && (unsigned)gx < WW) v = ib[gy * WW + gx];
    si[i * 36 + j] = v;
  }
  __syncthreads();

  // ---- edges strip (per-thread, 4 px): softsign(Σ relu(conv3x3)) ----
  {
    const int oy = tid >> 3, ox = (tid & 7) * 4;
    const int gy = by + oy, gx = bx + ox;

    float acc[8][4];
    #pragma unroll
    for (int c = 0; c < 8; ++c)
      #pragma unroll
      for (int t = 0; t < 4; ++t) acc[c][t] = 0.f;
    #pragma unroll
    for (int p = 0; p < 3; ++p) {
      const float* srow = &si[(oy + p) * 36 + ox];
      float4 r4 = *reinterpret_cast<const float4*>(srow);
      float2 r2 = *reinterpret_cast<const float2*>(srow + 4);
      float r[6] = {r4.x, r4.y, r4.z, r4.w, r2.x, r2.y};
      #pragma unroll
      for (int q = 0; q < 3; ++q) {
        float4 w0 = *reinterpret_cast<const float4*>(&ws[(p * 3 + q) * 8]);
        float4 w1 = *reinterpret_cast<const float4*>(&ws[(p * 3 + q) * 8 + 4]);
        #pragma unroll
        for (int t = 0; t < 4; ++t) {
          float v = r[q + t];
          acc[0][t] = fmaf(v, w0.x, acc[0][t]);
          acc[1][t] = fmaf(v, w0.y, acc[1][t]);
          acc[2][t] = fmaf(v, w0.z, acc[2][t]);
          acc[3][t] = fmaf(v, w0.w, acc[3][t]);
          acc[4][t] = fmaf(v, w1.x, acc[4][t]);
          acc[5][t] = fmaf(v, w1.y, acc[5][t]);
          acc[6][t] = fmaf(v, w1.z, acc[6][t]);
          acc[7][t] = fmaf(v, w1.w, acc[7][t]);
        }
      }
    }
    float ev[4];
    #pragma unroll
    for (int t = 0; t < 4; ++t) {
      float e = 0.f;
      #pragma unroll
      for (int c = 0; c < 8; ++c) e += fmaxf(acc[c][t], 0.f);
      ev[t] = e / (1.f + e);
    }
    float* erow = maps + E0 + (size_t)b * MAPB + (size_t)gy * MAPW + 4 + gx;
    *reinterpret_cast<float4*>(erow) = make_float4(ev[0], ev[1], ev[2], ev[3]);

    if (bx == 0 && (tid & 7) == 0) {
      float4 z = make_float4(0.f, 0.f, 0.f, 0.f);
      *reinterpret_cast<float4*>(maps + E0 + (size_t)b * MAPB + (size_t)gy * MAPW) = z;
      *reinterpret_cast<float4*>(maps + K0 + (size_t)b * MAPB + (size_t)gy * MAPW) = z;
    }
    if (bx == WW - T && (tid & 7) == 7) {
      float4 z = make_float4(0.f, 0.f, 0.f, 0.f);
      *reinterpret_cast<float4*>(maps + E0 + (size_t)b * MAPB + (size_t)gy * MAPW + 516) = z;
      *reinterpret_cast<float4*>(maps + K0 + (size_t)b * MAPB + (size_t)gy * MAPW + 516) = z;
    }
  }

  // ---- kappa via Toeplitz MFMA: wave wv -> 16x16 subtile (sty,stx) ----
  {
    const int lane = tid & 63;
    const int wv   = tid >> 6;
    const int q    = lane >> 4;
    const int n    = lane & 15;
    const int sty  = wv >> 1, stx = wv & 1;

    const unsigned short* KT = ((const unsigned short*)ws) + KT0 * 2;

    float4v acc = {0.f, 0.f, 0.f, 0.f};
    #pragma unroll
    for (int bb = 0; bb < 11; ++bb) {
      short8 af = *reinterpret_cast<const short8*>(KT + (bb * 64 + lane) * 8);
      // B[k][n] = u[by + sty*16 + k - 8][bx + stx*16 + n + bb - 5]
      short8 bf = *reinterpret_cast<const short8*>(
          &suT[(stx * 16 + n + bb) * 56 + sty * 16 + q * 8]);
      acc = __builtin_amdgcn_mfma_f32_16x16x32_bf16(af, bf, acc, 0, 0, 0);
    }
    // C: col = n, row = q*4 + i  ->  pixel (by+sty*16+q*4+i, bx+stx*16+n)
    float* kmapb = maps + K0 + (size_t)b * MAPB;
    #pragma unroll
    for (int i = 0; i < 4; ++i) {
      int yy = by + sty * 16 + q * 4 + i;
      int xx = bx + stx * 16 + n;
      kmapb[(size_t)yy * MAPW + 4 + xx] = acc[i] * kk[(size_t)yy * WW + xx];
    }
  }
}

// ---------------- kernel B v3 (unchanged R10): transposed MFMA grads -------
__global__ __launch_bounds__(256) void kernelB(
    const float* __restrict__ u,
    const float* __restrict__ sm,
    const float* maps, float* __restrict__ out) {
  __shared__ float sgx[32 * 32];
  __shared__ float sgy[32 * 32];

  const int bx = blockIdx.x * T, by = blockIdx.y * T, b = blockIdx.z;
  const int tid = threadIdx.x;
  const float* emap = maps + E0 + (size_t)b * MAPB;
  const float* kmap = maps + K0 + (size_t)b * MAPB;
  const float* ub   = u + (size_t)b * HH * WW;

  const int lane = tid & 63;
  const int wv   = tid >> 6;
  const int q    = lane >> 4;
  const int m    = lane & 15;

  short8 afr[4];
  {
    const unsigned short* F = ((const unsigned short*)maps) + F0 * 2;
    #pragma unroll
    for (int t = 0; t < 4; ++t)
      afr[t] = *reinterpret_cast<const short8*>(F + (t * 64 + lane) * 8);
  }

  const int gy0 = by + wv * 8;

  #pragma unroll
  for (int h = 0; h < 32; h += 16) {
    const int gxl = bx + h + m;
    const float* colp = emap + 4 + gxl - 1;

    unsigned short W[9];
    #pragma unroll
    for (int d = 0; d < 3; ++d) {
      int ry = gy0 - 1 + d;
      int rc = ry < 0 ? 0 : (ry > HH - 1 ? HH - 1 : ry);
      float msk = (ry == rc) ? 1.f : 0.f;
      const float* rp = colp + (size_t)rc * MAPW;
      W[3 * d + 0] = f2bf(rp[0] * msk);
      W[3 * d + 1] = f2bf(rp[1] * msk);
      W[3 * d + 2] = f2bf(rp[2] * msk);
    }

    #pragma unroll
    for (int r = 0; r < 8; ++r) {
      short8 bv = (short8)0;
      if (q == 0) {
        #pragma unroll
        for (int j = 0; j < 8; ++j) bv[j] = (short)W[j];
      } else if (q == 1) {
        bv[0] = (short)W[8];
      }

      float4v c0 = {0.f, 0.f, 0.f, 0.f}, c1 = c0, c2 = c0, c3 = c0;
      c0 = __builtin_amdgcn_mfma_f32_16x16x32_bf16(afr[0], bv, c0, 0, 0, 0);
      c1 = __builtin_amdgcn_mfma_f32_16x16x32_bf16(afr[1], bv, c1, 0, 0, 0);
      c2 = __builtin_amdgcn_mfma_f32_16x16x32_bf16(afr[2], bv, c2, 0, 0, 0);
      c3 = __builtin_amdgcn_mfma_f32_16x16x32_bf16(afr[3], bv, c3, 0, 0, 0);

      float rx = 0.f, ry = 0.f;
      #pragma unroll
      for (int i = 0; i < 4; ++i) {
        rx += fmaxf(c0[i], 0.f) + fmaxf(c1[i], 0.f);
        ry += fmaxf(c2[i], 0.f) + fmaxf(c3[i], 0.f);
      }
      rx += __shfl_xor(rx, 16); rx += __shfl_xor(rx, 32);
      ry += __shfl_xor(ry, 16); ry += __shfl_xor(ry, 32);

      if (q == 0) {
        sgx[(wv * 8 + r) * 32 + h + m] = rx;
        sgy[(wv * 8 + r) * 32 + h + m] = ry;
      }

      if (r < 7) {
        #pragma unroll
        for (int t = 0; t < 6; ++t) W[t] = W[t + 3];
        int ryn = gy0 + r + 2;
        int rcn = ryn < 0 ? 0 : (ryn > HH - 1 ? HH - 1 : ryn);
        float msk = (ryn == rcn) ? 1.f : 0.f;
        const float* rp = colp + (size_t)rcn * MAPW;
        W[6] = f2bf(rp[0] * msk);
        W[7] = f2bf(rp[1] * msk);
        W[8] = f2bf(rp[2] * msk);
      }
    }
  }
  __syncthreads();

  {
    const int oy = tid >> 3, ox = (tid & 7) * 4;
    const int gy = by + oy, gx = bx + ox;

    float4 gx4 = *reinterpret_cast<const float4*>(&sgx[oy * 32 + ox]);
    float4 gy4 = *reinterpret_cast<const float4*>(&sgy[oy * 32 + ox]);
    float gxa[4] = {gx4.x, gx4.y, gx4.z, gx4.w};
    float gya[4] = {gy4.x, gy4.y, gy4.z, gy4.w};

    float4 ec4 = *reinterpret_cast<const float4*>(&emap[(size_t)gy * MAPW + 4 + gx]);
    float ec[4] = {ec4.x, ec4.y, ec4.z, ec4.w};

    float kap[4] = {0.f, 0.f, 0.f, 0.f};
    #pragma unroll
    for (int m5 = 0; m5 < 5; ++m5) {
      int ry = gy - 2 + m5;
      int rc = ry < 0 ? 0 : (ry > HH - 1 ? HH - 1 : ry);
      float msk = (ry == rc) ? 1.f : 0.f;
      const float* row = kmap + (size_t)rc * MAPW + 4 + gx;
      float2 a  = *reinterpret_cast<const float2*>(row - 2);
      float4 c4 = *reinterpret_cast<const float4*>(row);
      float2 d2 = *reinterpret_cast<const float2*>(row + 4);
      float r[8] = {a.x, a.y, c4.x, c4.y, c4.z, c4.w, d2.x, d2.y};
      #pragma unroll
      for (int n = 0; n < 5; ++n) {
        float w = sm[m5 * 5 + n] * msk;
        #pragma unroll
        for (int t = 0; t < 4; ++t) kap[t] = fmaf(r[t + n], w, kap[t]);
      }
    }

    const float* ur = ub + (size_t)gy * WW + gx;
    float4 uc4 = *reinterpret_cast<const float4*>(ur);
    int jm = gx > 0 ? -1 : 0;
    float ul = ur[jm];
    ul = gx > 0 ? ul : 0.f;
    int ryd = gy < HH - 1 ? gy + 1 : HH - 1;
    float md = gy < HH - 1 ? 1.f : 0.f;
    float4 ud4 = *reinterpret_cast<const float4*>(ub + (size_t)ryd * WW + gx);

    float uc[4]  = {uc4.x, uc4.y, uc4.z, uc4.w};
    float ulx[4] = {ul, uc4.x, uc4.y, uc4.z};
    float udn[4] = {ud4.x * md, ud4.y * md, ud4.z * md, ud4.w * md};

    float res[4];
    #pragma unroll
    for (int t = 0; t < 4; ++t) {
      float xp = uc[t] - ulx[t];
      float yp = uc[t] - udn[t];
      res[t] = uc[t] + gxa[t] * xp + gya[t] * yp + ec[t] + kap[t];
    }
    *reinterpret_cast<float4*>(&out[((size_t)b * HH + gy) * WW + gx]) =
        make_float4(res[0], res[1], res[2], res[3]);
  }
}

// ---------------- Fallback: R3 monolith (used if ws too small) --------------
__global__ __launch_bounds__(256) void forcing_main(
    const float* __restrict__ u, const float* __restrict__ img,
    const float* __restrict__ kx, const float* __restrict__ ky,
    const float* __restrict__ sm, const float* __restrict__ kk,
    const float* __restrict__ ws, float* __restrict__ out) {
  __shared__ float su[46][48];
  __shared__ float si[36][37];
  __shared__ float se[34][35];
  __shared__ float sk[36][37];
  __shared__ float w_edge[72];
  __shared__ float w_kx[288];
  __shared__ float w_ky[288];
  __shared__ float w_k11[124];
  __shared__ float w_sm[28];

  const int bx = blockIdx.x * T;
  const int by = blockIdx.y * T;
  const int b  = blockIdx.z;
  const int tid = threadIdx.x;
  const float* ub = u   + (size_t)b * HH * WW;
  const float* ib = img + (size_t)b * HH * WW;

  for (int i = tid; i < 72; i += 256)  w_edge[i] = ws[i];
  for (int i = tid; i < 121; i += 256) w_k11[i]  = ws[72 + i];
  for (int i = tid; i < 288; i += 256) { w_kx[i] = kx[i]; w_ky[i] = ky[i]; }
  if (tid < 25) w_sm[tid] = sm[tid];

  for (int idx = tid; idx < 46 * 46; idx += 256) {
    int i = idx / 46, j = idx % 46;
    int gy = by - 7 + i, gx = bx - 7 + j;
    float v = 0.f;
    if ((unsigned)gy < HH && (unsigned)gx < WW) v = ub[gy * WW + gx];
    su[i][j] = v;
  }
  for (int idx = tid; idx < 36 * 36; idx += 256) {
    int i = idx / 36, j = idx % 36;
    int gy = by - 2 + i, gx = bx - 2 + j;
    float v = 0.f;
    if ((unsigned)gy < HH && (unsigned)gx < WW) v = ib[gy * WW + gx];
    si[i][j] = v;
  }
  __syncthreads();

  for (int idx = tid; idx < 34 * 9; idx += 256) {
    int i = idx / 9, j0 = (idx % 9) * 4;
    float acc[8][4];
    #pragma unroll
    for (int c = 0; c < 8; ++c)
      #pragma unroll
      for (int t = 0; t < 4; ++t) acc[c][t] = 0.f;
    #pragma unroll
    for (int p = 0; p < 3; ++p) {
      float r[6];
      #pragma unroll
      for (int t = 0; t < 6; ++t) r[t] = si[i + p][j0 + t];
      #pragma unroll
      for (int q = 0; q < 3; ++q) {
        const float4 w0 = *reinterpret_cast<const float4*>(&w_edge[(p * 3 + q) * 8]);
        const float4 w1 = *reinterpret_cast<const float4*>(&w_edge[(p * 3 + q) * 8 + 4]);
        #pragma unroll
        for (int t = 0; t < 4; ++t) {
          float v = r[q + t];
          acc[0][t] = fmaf(v, w0.x, acc[0][t]);
          acc[1][t] = fmaf(v, w0.y, acc[1][t]);
          acc[2][t] = fmaf(v, w0.z, acc[2][t]);
          acc[3][t] = fmaf(v, w0.w, acc[3][t]);
          acc[4][t] = fmaf(v, w1.x, acc[4][t]);
          acc[5][t] = fmaf(v, w1.y, acc[5][t]);
          acc[6][t] = fmaf(v, w1.z, acc[6][t]);
          acc[7][t] = fmaf(v, w1.w, acc[7][t]);
        }
      }
    }
    int gy = by - 1 + i;
    #pragma unroll
    for (int t = 0; t < 4; ++t) {
      int j = j0 + t;
      if (j < 34) {
        int gx = bx - 1 + j;
        float val = 0.f;
        if ((unsigned)gy < HH && (unsigned)gx < WW) {
          float e = 0.f;
          #pragma unroll
          for (int c = 0; c < 8; ++c) e += fmaxf(acc[c][t], 0.f);
          val = e / (1.f + e);
        }
        se[i][j] = val;
      }
    }
  }

  for (int idx = tid; idx < 36 * 9; idx += 256) {
    int i = idx / 9, js = (idx % 9) * 4;
    float o0 = 0.f, o1 = 0.f, o2 = 0.f, o3 = 0.f;
    #pragma unroll
    for (int A = 0; A < 11; ++A) {
      const float* row = &su[i + A][js];
      float4 v0 = *reinterpret_cast<const float4*>(row);
      float4 v1 = *reinterpret_cast<const float4*>(row + 4);
      float4 v2 = *reinterpret_cast<const float4*>(row + 8);
      float r[14] = {v0.x, v0.y, v0.z, v0.w, v1.x, v1.y, v1.z, v1.w,
                     v2.x, v2.y, v2.z, v2.w, row[12], row[13]};
      #pragma unroll
      for (int B2 = 0; B2 < 11; ++B2) {
        float w = w_k11[A * 11 + B2];
        o0 = fmaf(r[B2],     w, o0);
        o1 = fmaf(r[B2 + 1], w, o1);
        o2 = fmaf(r[B2 + 2], w, o2);
        o3 = fmaf(r[B2 + 3], w, o3);
      }
    }
    int gy = by - 2 + i;
    float o[4] = {o0, o1, o2, o3};
    #pragma unroll
    for (int t = 0; t < 4; ++t) {
      int gx = bx - 2 + js + t;
      float val = 0.f;
      if ((unsigned)gy < HH && (unsigned)gx < WW) val = o[t] * kk[gy * WW + gx];
      sk[i][js + t] = val;
    }
  }
  __syncthreads();

  {
    const int oy = tid >> 3;
    const int ox = (tid & 7) * 4;
    const int gy = by + oy;
    const int gx = bx + ox;

    float e[3][6];
    #pragma unroll
    for (int p = 0; p < 3; ++p)
      #pragma unroll
      for (int t = 0; t < 6; ++t) e[p][t] = se[oy + p][ox + t];

    const float4* wx4 = reinterpret_cast<const float4*>(w_kx);
    const float4* wy4 = reinterpret_cast<const float4*>(w_ky);

    float gxa[4] = {0.f, 0.f, 0.f, 0.f};
    float gya[4] = {0.f, 0.f, 0.f, 0.f};
    #pragma unroll
    for (int cq = 0; cq < 8; ++cq) {
      float sx[4][4], sy[4][4];
      #pragma unroll
      for (int cc = 0; cc < 4; ++cc)
        #pragma unroll
        for (int t = 0; t < 4; ++t) { sx[cc][t] = 0.f; sy[cc][t] = 0.f; }
      #pragma unroll
      for (int p = 0; p < 3; ++p)
        #pragma unroll
        for (int q = 0; q < 3; ++q) {
          float4 wx = wx4[(p * 3 + q) * 8 + cq];
          float4 wy = wy4[(p * 3 + q) * 8 + cq];
          #pragma unroll
          for (int t = 0; t < 4; ++t) {
            float evv = e[p][q + t];
            sx[0][t] = fmaf(evv, wx.x, sx[0][t]);
            sx[1][t] = fmaf(evv, wx.y, sx[1][t]);
            sx[2][t] = fmaf(evv, wx.z, sx[2][t]);
            sx[3][t] = fmaf(evv, wx.w, sx[3][t]);
            sy[0][t] = fmaf(evv, wy.x, sy[0][t]);
            sy[1][t] = fmaf(evv, wy.y, sy[1][t]);
            sy[2][t] = fmaf(evv, wy.z, sy[2][t]);
            sy[3][t] = fmaf(evv, wy.w, sy[3][t]);
          }
        }
      #pragma unroll
      for (int cc = 0; cc < 4; ++cc)
        #pragma unroll
        for (int t = 0; t < 4; ++t) {
          gxa[t] += fmaxf(sx[cc][t], 0.f);
          gya[t] += fmaxf(sy[cc][t], 0.f);
        }
    }

    float res[4];
    #pragma unroll
    for (int t = 0; t < 4; ++t) {
      float kap = 0.f;
      #pragma unroll
      for (int m = 0; m < 5; ++m)
        #pragma unroll
        for (int n = 0; n < 5; ++n)
          kap = fmaf(sk[oy + m][ox + t + n], w_sm[m * 5 + n], kap);

      float uc = su[oy + 7][ox + 7 + t];
      float xp = uc - su[oy + 7][ox + 6 + t];
      float yp = uc - su[oy + 8][ox + 7 + t];
      float ec = se[oy + 1][ox + 1 + t];
      res[t] = uc + gxa[t] * xp + gya[t] * yp + ec + kap;
    }

    float4 r4 = make_float4(res[0], res[1], res[2], res[3]);
    *reinterpret_cast<float4*>(&out[((size_t)b * HH + gy) * WW + gx]) = r4;
  }
}

extern "C" void kernel_launch(void* const* d_in, const int* in_sizes, int n_in,
                              void* d_out, int out_size, void* d_ws, size_t ws_size,
                              hipStream_t stream) {
  const float* u   = (const float*)d_in[0];
  const float* img = (const float*)d_in[1];
  const float* kx  = (const float*)d_in[2];
  const float* ky  = (const float*)d_in[3];
  const float* kd  = (const float*)d_in[4];
  const float* kp  = (const float*)d_in[5];
  const float* k0  = (const float*)d_in[6];
  const float* k1  = (const float*)d_in[7];
  const float* k2  = (const float*)d_in[8];
  const float* sm  = (const float*)d_in[9];
  const float* kk  = (const float*)d_in[10];
  float* out = (float*)d_out;
  float* ws  = (float*)d_ws;

  precompute_kernels<<<1, 256, 0, stream>>>(kd, kp, k0, k1, k2, kx, ky, ws);
  dim3 grid(WW / T, HH / T, BB);
  if (ws != nullptr && ws_size >= WS_NEEDED_BYTES) {
    kernelA<<<grid, 256, 0, stream>>>(u, img, kk, ws, ws);
    kernelB<<<grid, 256, 0, stream>>>(u, sm, ws, out);
  } else {
    forcing_main<<<grid, 256, 0, stream>>>(u, img, kx, ky, sm, kk, ws, out);
  }
}